// Round 1
// baseline (3204.534 us; speedup 1.0000x reference)
//
#include <hip/hip_runtime.h>

// ---------------- constants / layout ----------------
constexpr int HW = 512 * 512; // 262144

// d_out layout (floats): albedo_tex (1,3,512,512) | final (2,3,512,512) |
//                        fwd_term (2,3,512,512)   | albedo (2,3,512,512)
constexpr long OUT_ATEX  = 0;
constexpr long OUT_FINAL = 786432;
constexpr long OUT_FWD   = 786432 + 1572864;          // 2359296
constexpr long OUT_ALB   = 786432 + 2L * 1572864;     // 3932160

// workspace layout (floats)
constexpr long OFF_M   = 0;                  // m: (2,9,512,512)  = 4,718,592
constexpr long OFF_NT  = 4718592;            // nt:(2,16,512,512) = 8,388,608 (dies after d1)
constexpr long OFF_D2C = 4718592;            // d2cat:(2,128,128,128)=4,194,304 (aliases nt)
constexpr long OFF_D3  = 4718592 + 4194304;  // d3:(2,128,64,64) = 1,048,576
constexpr long OFF_D1C = 4718592 + 8388608;  // d1cat:(2,64,256,256)=8,388,608
// total = 21,495,808 floats = ~86 MB

// ---------------- bilinear sampling ----------------
__device__ __forceinline__ void bl_setup(float u, float v, int T,
                                         int& x0, int& y0, float& wx, float& wy) {
  float px = u * (float)(T - 1);
  float py = v * (float)(T - 1);
  int xi = (int)floorf(px);
  int yi = (int)floorf(py);
  xi = xi < 0 ? 0 : (xi > T - 2 ? T - 2 : xi);
  yi = yi < 0 ? 0 : (yi > T - 2 ? T - 2 : yi);
  wx = px - (float)xi;
  wy = py - (float)yi;
  x0 = xi; y0 = yi;
}

template<int C, int T>
__device__ __forceinline__ void sample_acc(const float* __restrict__ tex,
                                           float u, float v, float* o) {
  int x0, y0; float wx, wy;
  bl_setup(u, v, T, x0, y0, wx, wy);
  float w00 = (1.f - wx) * (1.f - wy), w01 = wx * (1.f - wy);
  float w10 = (1.f - wx) * wy,         w11 = wx * wy;
  const float* b = tex + y0 * T + x0;
  #pragma unroll
  for (int c = 0; c < C; ++c) {
    o[c] += b[0] * w00 + b[1] * w01 + b[T] * w10 + b[T + 1] * w11;
    b += T * T;
  }
}

// ---------------- stage A: sample + SH reduce ----------------
__global__ __launch_bounds__(256) void sample_sh_k(
    const float* __restrict__ wi, const float* __restrict__ env,
    const float* __restrict__ uv, const float* __restrict__ ext,
    const float* __restrict__ atex,
    const float* __restrict__ t1, const float* __restrict__ t2,
    const float* __restrict__ t3, const float* __restrict__ t4,
    float* __restrict__ m_out, float* __restrict__ nt_out,
    float* __restrict__ dout) {
  int idx = blockIdx.x * 256 + threadIdx.x;   // 0 .. 524287
  int n = idx >> 18;
  int p = idx & (HW - 1);

  float2 uvv = reinterpret_cast<const float2*>(uv)[idx];
  float u = uvv.x, v = uvv.y;

  float alb[3] = {0.f, 0.f, 0.f};
  sample_acc<3, 512>(atex, u, v, alb);

  float nt[16];
  #pragma unroll
  for (int c = 0; c < 16; ++c) nt[c] = 0.f;
  sample_acc<16, 512>(t1, u, v, nt);
  sample_acc<16, 256>(t2, u, v, nt);
  sample_acc<16, 128>(t3, u, v, nt);
  sample_acc<16, 64>(t4, u, v, nt);

  const float C0f = 0.28209479177387814f, C1f = 0.4886025119029199f;
  const float C2f = 1.0925484305920792f, C20f = 0.31539156525252005f;
  const float C22f = 0.5462742152960396f;
  const float SQ = 0.70710678118654752f;

  float ex = ext[n * 3 + 0], ey = ext[n * 3 + 1], ez = ext[n * 3 + 2];
  float basis[9];
  basis[0] = C0f;
  basis[1] = ey * C1f * SQ;
  basis[2] = ez * C1f;
  basis[3] = -ex * C1f * SQ;
  basis[4] = ex * ey * C2f * 0.5f * SQ;
  basis[5] = ey * ez * C2f * SQ;
  basis[6] = (3.f * ez * ez - 1.f) * C20f;
  basis[7] = -ez * ex * C2f * SQ;
  basis[8] = (ex * ex - ez * ez) * C2f * 0.5f * SQ;
  #pragma unroll
  for (int j = 0; j < 9; ++j) nt[3 + j] *= basis[j];

  float ms[8];
  #pragma unroll
  for (int j = 0; j < 8; ++j) ms[j] = 0.f;
  float es[3] = {0.f, 0.f, 0.f};

  const float* wb = wi + ((long)n * 20) * HW + p;
  const float* eb = env + ((long)n * 30) * HW + p;
  #pragma unroll
  for (int ss = 0; ss < 10; ++ss) {
    float th = wb[(long)ss * HW];
    float ph = wb[(long)(10 + ss) * HW];
    float st, ct, sp, cp;
    sincosf(th, &st, &ct);
    sincosf(ph, &sp, &cp);
    float x = st * cp, y = st * sp, z = ct;
    ms[0] += y; ms[1] += z; ms[2] += x;
    ms[3] += x * y; ms[4] += y * z;
    ms[5] += 3.f * z * z - 1.f;
    ms[6] += x * z; ms[7] += x * x - y * y;
    es[0] += eb[(long)ss * HW];
    es[1] += eb[(long)(10 + ss) * HW];
    es[2] += eb[(long)(20 + ss) * HW];
  }

  float m[9];
  m[0] = C0f;
  m[1] = C1f * ms[0] * 0.1f; m[2] = C1f * ms[1] * 0.1f; m[3] = C1f * ms[2] * 0.1f;
  m[4] = C2f * ms[3] * 0.1f; m[5] = C2f * ms[4] * 0.1f; m[6] = C20f * ms[5] * 0.1f;
  m[7] = C2f * ms[6] * 0.1f; m[8] = C22f * ms[7] * 0.1f;

  #pragma unroll
  for (int k = 0; k < 9; ++k) m_out[((long)n * 9 + k) * HW + p] = m[k];
  #pragma unroll
  for (int c = 0; c < 16; ++c) nt_out[((long)n * 16 + c) * HW + p] = nt[c];
  #pragma unroll
  for (int c = 0; c < 3; ++c) {
    dout[OUT_FWD + ((long)n * 3 + c) * HW + p] = alb[c] * es[c] * 0.1f;
    dout[OUT_ALB + ((long)n * 3 + c) * HW + p] = alb[c];
  }
}

// ---------------- albedo_tex copy ----------------
__global__ __launch_bounds__(256) void copy4_k(const float4* __restrict__ s,
                                               float4* __restrict__ d, int n) {
  int i = blockIdx.x * 256 + threadIdx.x;
  if (i < n) d[i] = s[i];
}

// ---------------- generic fused conv3x3 ----------------
// 16x16 output tile per block (256 threads). LDS-staged input in CK=8 channel
// chunks. UP=2 folds nearest-neighbor up2 into the load. Stride2 uses JAX SAME
// pad_lo=0; stride1 pad_lo=1. Weight addresses are wave-uniform -> s_loads.
template<int CIN, int COUT_BLK, int NOCB, int STRIDE, int UP, int OH, int OW,
         bool RELU, bool FUSE>
__global__ __launch_bounds__(256) void conv3x3_k(
    const float* __restrict__ in, long in_nstride,
    const float* __restrict__ wgt, const float* __restrict__ bias,
    float* __restrict__ out, long out_nstride, int out_coff,
    const float* __restrict__ m_in, const float* __restrict__ alb_in,
    float* __restrict__ fin_out) {
  constexpr int TI = 16 * STRIDE + 2;
  constexpr int CK = 8;
  constexpr int VH = OH * STRIDE, VW = OW * STRIDE;
  constexpr int SH = VH / UP, SW = VW / UP;
  constexpr long OHW = (long)OH * OW;
  __shared__ float lds[CK][TI][TI];

  int tid = threadIdx.x;
  int ox = tid & 15, oy = tid >> 4;
  int tileX = blockIdx.x, tileY = blockIdx.y;
  int z = blockIdx.z;
  int n = z / NOCB;
  int oc_base = (z % NOCB) * COUT_BLK;
  int gx0 = tileX * 16 * STRIDE - (STRIDE == 1 ? 1 : 0);
  int gy0 = tileY * 16 * STRIDE - (STRIDE == 1 ? 1 : 0);

  float acc[COUT_BLK];
  #pragma unroll
  for (int i = 0; i < COUT_BLK; ++i) acc[i] = 0.f;

  for (int c0 = 0; c0 < CIN; c0 += CK) {
    constexpr int TOT = CK * TI * TI;
    for (int i = tid; i < TOT; i += 256) {
      int c = i / (TI * TI);
      int r = i - c * (TI * TI);
      int iy = r / TI;
      int ix = r - iy * TI;
      int gy = gy0 + iy, gx = gx0 + ix;
      float val = 0.f;
      if ((unsigned)gy < (unsigned)VH && (unsigned)gx < (unsigned)VW) {
        int sy = (UP == 2) ? (gy >> 1) : gy;
        int sx = (UP == 2) ? (gx >> 1) : gx;
        val = in[(long)n * in_nstride + (long)(c0 + c) * (SH * SW) + sy * SW + sx];
      }
      lds[c][iy][ix] = val;
    }
    __syncthreads();
    #pragma unroll
    for (int c = 0; c < CK; ++c) {
      float v[9];
      #pragma unroll
      for (int ky = 0; ky < 3; ++ky)
        #pragma unroll
        for (int kx = 0; kx < 3; ++kx)
          v[ky * 3 + kx] = lds[c][oy * STRIDE + ky][ox * STRIDE + kx];
      #pragma unroll
      for (int oc = 0; oc < COUT_BLK; ++oc) {
        const float* w9 = wgt + ((long)(oc_base + oc) * CIN + (c0 + c)) * 9;
        #pragma unroll
        for (int t = 0; t < 9; ++t) acc[oc] = fmaf(w9[t], v[t], acc[oc]);
      }
    }
    __syncthreads();
  }

  int oyg = tileY * 16 + oy, oxg = tileX * 16 + ox;
  long pix = (long)oyg * OW + oxg;

  if constexpr (!FUSE) {
    #pragma unroll
    for (int oc = 0; oc < COUT_BLK; ++oc) {
      float x = acc[oc] + bias[oc_base + oc];
      if (RELU) x = x >= 0.f ? x : 0.2f * x;
      out[(long)n * out_nstride + (long)(out_coff + oc_base + oc) * OHW + pix] = x;
    }
  } else {
    // COUT_BLK == 27 : T channels 3k+c; final_c = albedo_c * sum_k m_k * T[3k+c]
    float s0 = 0.f, s1 = 0.f, s2 = 0.f;
    #pragma unroll
    for (int k = 0; k < 9; ++k) {
      float mk = m_in[((long)n * 9 + k) * OHW + pix];
      s0 = fmaf(mk, acc[3 * k + 0] + bias[3 * k + 0], s0);
      s1 = fmaf(mk, acc[3 * k + 1] + bias[3 * k + 1], s1);
      s2 = fmaf(mk, acc[3 * k + 2] + bias[3 * k + 2], s2);
    }
    float a0 = alb_in[((long)n * 3 + 0) * OHW + pix];
    float a1 = alb_in[((long)n * 3 + 1) * OHW + pix];
    float a2 = alb_in[((long)n * 3 + 2) * OHW + pix];
    fin_out[((long)n * 3 + 0) * OHW + pix] = a0 * s0;
    fin_out[((long)n * 3 + 1) * OHW + pix] = a1 * s1;
    fin_out[((long)n * 3 + 2) * OHW + pix] = a2 * s2;
  }
}

// ---------------- launch ----------------
extern "C" void kernel_launch(void* const* d_in, const int* in_sizes, int n_in,
                              void* d_out, int out_size, void* d_ws, size_t ws_size,
                              hipStream_t stream) {
  const float* wi   = (const float*)d_in[0];
  const float* env  = (const float*)d_in[1];
  const float* uv   = (const float*)d_in[2];
  const float* ext  = (const float*)d_in[3];
  const float* atex = (const float*)d_in[4];
  const float* t1   = (const float*)d_in[5];
  const float* t2   = (const float*)d_in[6];
  const float* t3   = (const float*)d_in[7];
  const float* t4   = (const float*)d_in[8];
  const float* w_d1 = (const float*)d_in[9];
  const float* b_d1 = (const float*)d_in[10];
  const float* w_d2 = (const float*)d_in[11];
  const float* b_d2 = (const float*)d_in[12];
  const float* w_d3 = (const float*)d_in[13];
  const float* b_d3 = (const float*)d_in[14];
  const float* w_u3 = (const float*)d_in[15];
  const float* b_u3 = (const float*)d_in[16];
  const float* w_u2 = (const float*)d_in[17];
  const float* b_u2 = (const float*)d_in[18];
  const float* w_u1 = (const float*)d_in[19];
  const float* b_u1 = (const float*)d_in[20];
  float* out = (float*)d_out;
  float* ws  = (float*)d_ws;

  float* m_buf = ws + OFF_M;
  float* nt_buf = ws + OFF_NT;
  float* d2cat = ws + OFF_D2C;
  float* d3buf = ws + OFF_D3;
  float* d1cat = ws + OFF_D1C;

  // stage A: bilinear samples + SH means + fwd_term + albedo outputs
  sample_sh_k<<<2048, 256, 0, stream>>>(wi, env, uv, ext, atex, t1, t2, t3, t4,
                                        m_buf, nt_buf, out);
  // albedo_tex copy
  copy4_k<<<768, 256, 0, stream>>>((const float4*)atex, (float4*)out, 196608);

  // d1: nt(16,512^2) -> d1cat[32:64] (32,256^2), stride2
  conv3x3_k<16, 32, 1, 2, 1, 256, 256, true, false><<<dim3(16, 16, 2), 256, 0, stream>>>(
      nt_buf, 16L * HW, w_d1, b_d1, d1cat, 64L * 65536, 32, nullptr, nullptr, nullptr);
  // d2: d1cat[32:64](32,256^2) -> d2cat[64:128] (64,128^2), stride2
  conv3x3_k<32, 32, 2, 2, 1, 128, 128, true, false><<<dim3(8, 8, 4), 256, 0, stream>>>(
      d1cat + 32L * 65536, 64L * 65536, w_d2, b_d2, d2cat, 128L * 16384, 64,
      nullptr, nullptr, nullptr);
  // d3: d2cat[64:128](64,128^2) -> d3 (128,64^2), stride2
  conv3x3_k<64, 16, 8, 2, 1, 64, 64, true, false><<<dim3(4, 4, 16), 256, 0, stream>>>(
      d2cat + 64L * 16384, 128L * 16384, w_d3, b_d3, d3buf, 128L * 4096, 0,
      nullptr, nullptr, nullptr);
  // u3: up2(d3)(128,128^2 view) -> d2cat[0:64] (64,128^2), stride1
  conv3x3_k<128, 16, 4, 1, 2, 128, 128, true, false><<<dim3(8, 8, 8), 256, 0, stream>>>(
      d3buf, 128L * 4096, w_u3, b_u3, d2cat, 128L * 16384, 0, nullptr, nullptr, nullptr);
  // u2: up2(d2cat)(128,256^2 view) -> d1cat[0:32] (32,256^2), stride1
  conv3x3_k<128, 32, 1, 1, 2, 256, 256, true, false><<<dim3(16, 16, 2), 256, 0, stream>>>(
      d2cat, 128L * 16384, w_u2, b_u2, d1cat, 64L * 65536, 0, nullptr, nullptr, nullptr);
  // u1 fused: up2(d1cat)(64,512^2 view) -> T(27,512^2) -> final
  conv3x3_k<64, 27, 1, 1, 2, 512, 512, false, true><<<dim3(32, 32, 2), 256, 0, stream>>>(
      d1cat, 64L * 65536, w_u1, b_u1, nullptr, 0, 0,
      m_buf, out + OUT_ALB, out + OUT_FINAL);
}

// Round 2
// 2491.064 us; speedup vs baseline: 1.2864x; 1.2864x over previous
//
#include <hip/hip_runtime.h>

// ---------------- constants / layout ----------------
constexpr int HW = 512 * 512; // 262144

// d_out layout (floats)
constexpr long OUT_FINAL = 786432;
constexpr long OUT_FWD   = 2359296;
constexpr long OUT_ALB   = 3932160;

// workspace layout (floats)
constexpr long OFF_M   = 0;                  // m: (2,9,512,512)
constexpr long OFF_NT  = 4718592;            // nt:(2,16,512,512)  dies after d1
constexpr long OFF_D2C = 4718592;            // d2cat:(2,128,128,128) aliases nt
constexpr long OFF_D3  = 8912896;            // d3:(2,128,64,64)
constexpr long OFF_WE3 = 9961472;            // weff u3: 64*128*16 = 131072
constexpr long OFF_WE2 = 10092544;           // weff u2: 32*128*16 = 65536
constexpr long OFF_WE1 = 10158080;           // weff u1: 27*64*16  = 27648
constexpr long OFF_D1C = 13107200;           // d1cat:(2,64,256,256)
// total 21,495,808 floats (~86 MB) — same footprint as round 1

// ---------------- bilinear sampling ----------------
__device__ __forceinline__ void bl_setup(float u, float v, int T,
                                         int& x0, int& y0, float& wx, float& wy) {
  float px = u * (float)(T - 1);
  float py = v * (float)(T - 1);
  int xi = (int)floorf(px);
  int yi = (int)floorf(py);
  xi = xi < 0 ? 0 : (xi > T - 2 ? T - 2 : xi);
  yi = yi < 0 ? 0 : (yi > T - 2 ? T - 2 : yi);
  wx = px - (float)xi;
  wy = py - (float)yi;
  x0 = xi; y0 = yi;
}

template<int C, int T>
__device__ __forceinline__ void sample_acc(const float* __restrict__ tex,
                                           float u, float v, float* o) {
  int x0, y0; float wx, wy;
  bl_setup(u, v, T, x0, y0, wx, wy);
  float w00 = (1.f - wx) * (1.f - wy), w01 = wx * (1.f - wy);
  float w10 = (1.f - wx) * wy,         w11 = wx * wy;
  const float* b = tex + y0 * T + x0;
  #pragma unroll
  for (int c = 0; c < C; ++c) {
    o[c] += b[0] * w00 + b[1] * w01 + b[T] * w10 + b[T + 1] * w11;
    b += T * T;
  }
}

// ---------------- stage A: sample + SH reduce ----------------
__global__ __launch_bounds__(256) void sample_sh_k(
    const float* __restrict__ wi, const float* __restrict__ env,
    const float* __restrict__ uv, const float* __restrict__ ext,
    const float* __restrict__ atex,
    const float* __restrict__ t1, const float* __restrict__ t2,
    const float* __restrict__ t3, const float* __restrict__ t4,
    float* __restrict__ m_out, float* __restrict__ nt_out,
    float* __restrict__ dout) {
  int idx = blockIdx.x * 256 + threadIdx.x;   // 0 .. 524287
  int n = idx >> 18;
  int p = idx & (HW - 1);

  float2 uvv = reinterpret_cast<const float2*>(uv)[idx];
  float u = uvv.x, v = uvv.y;

  float alb[3] = {0.f, 0.f, 0.f};
  sample_acc<3, 512>(atex, u, v, alb);

  float nt[16];
  #pragma unroll
  for (int c = 0; c < 16; ++c) nt[c] = 0.f;
  sample_acc<16, 512>(t1, u, v, nt);
  sample_acc<16, 256>(t2, u, v, nt);
  sample_acc<16, 128>(t3, u, v, nt);
  sample_acc<16, 64>(t4, u, v, nt);

  const float C0f = 0.28209479177387814f, C1f = 0.4886025119029199f;
  const float C2f = 1.0925484305920792f, C20f = 0.31539156525252005f;
  const float C22f = 0.5462742152960396f;
  const float SQ = 0.70710678118654752f;

  float ex = ext[n * 3 + 0], ey = ext[n * 3 + 1], ez = ext[n * 3 + 2];
  float basis[9];
  basis[0] = C0f;
  basis[1] = ey * C1f * SQ;
  basis[2] = ez * C1f;
  basis[3] = -ex * C1f * SQ;
  basis[4] = ex * ey * C2f * 0.5f * SQ;
  basis[5] = ey * ez * C2f * SQ;
  basis[6] = (3.f * ez * ez - 1.f) * C20f;
  basis[7] = -ez * ex * C2f * SQ;
  basis[8] = (ex * ex - ez * ez) * C2f * 0.5f * SQ;
  #pragma unroll
  for (int j = 0; j < 9; ++j) nt[3 + j] *= basis[j];

  float ms[8];
  #pragma unroll
  for (int j = 0; j < 8; ++j) ms[j] = 0.f;
  float es[3] = {0.f, 0.f, 0.f};

  const float* wb = wi + ((long)n * 20) * HW + p;
  const float* eb = env + ((long)n * 30) * HW + p;
  #pragma unroll
  for (int ss = 0; ss < 10; ++ss) {
    float th = wb[(long)ss * HW];
    float ph = wb[(long)(10 + ss) * HW];
    float st, ct, sp, cp;
    sincosf(th, &st, &ct);
    sincosf(ph, &sp, &cp);
    float x = st * cp, y = st * sp, z = ct;
    ms[0] += y; ms[1] += z; ms[2] += x;
    ms[3] += x * y; ms[4] += y * z;
    ms[5] += 3.f * z * z - 1.f;
    ms[6] += x * z; ms[7] += x * x - y * y;
    es[0] += eb[(long)ss * HW];
    es[1] += eb[(long)(10 + ss) * HW];
    es[2] += eb[(long)(20 + ss) * HW];
  }

  float m[9];
  m[0] = C0f;
  m[1] = C1f * ms[0] * 0.1f; m[2] = C1f * ms[1] * 0.1f; m[3] = C1f * ms[2] * 0.1f;
  m[4] = C2f * ms[3] * 0.1f; m[5] = C2f * ms[4] * 0.1f; m[6] = C20f * ms[5] * 0.1f;
  m[7] = C2f * ms[6] * 0.1f; m[8] = C22f * ms[7] * 0.1f;

  #pragma unroll
  for (int k = 0; k < 9; ++k) m_out[((long)n * 9 + k) * HW + p] = m[k];
  #pragma unroll
  for (int c = 0; c < 16; ++c) nt_out[((long)n * 16 + c) * HW + p] = nt[c];
  #pragma unroll
  for (int c = 0; c < 3; ++c) {
    dout[OUT_FWD + ((long)n * 3 + c) * HW + p] = alb[c] * es[c] * 0.1f;
    dout[OUT_ALB + ((long)n * 3 + c) * HW + p] = alb[c];
  }
}

// ---------------- albedo_tex copy ----------------
__global__ __launch_bounds__(256) void copy4_k(const float4* __restrict__ s,
                                               float4* __restrict__ d, int n) {
  int i = blockIdx.x * 256 + threadIdx.x;
  if (i < n) d[i] = s[i];
}

// ---------------- up2-folded weight expansion ----------------
// For out(2a+py, 2b+px) of conv3x3(up2(src), SAME pad 1):
// value = sum_{iy,ix in 0..1} W2[py][px][iy][ix] * src(a-1+py+iy, b-1+px+ix)
// W2 layout per (oc,ic): [(py*2+px)*4 + iy*2 + ix], 16 floats.
__global__ __launch_bounds__(256) void expand_w_k(const float* __restrict__ w,
                                                  float* __restrict__ weff,
                                                  int total) {
  int i = blockIdx.x * 256 + threadIdx.x;
  if (i >= total) return;
  float a[9];
  #pragma unroll
  for (int t = 0; t < 9; ++t) a[t] = w[(long)i * 9 + t];
  float colc[3][4]; // [ky][px*2+ix]
  #pragma unroll
  for (int ky = 0; ky < 3; ++ky) {
    colc[ky][0] = a[ky * 3 + 0];
    colc[ky][1] = a[ky * 3 + 1] + a[ky * 3 + 2];
    colc[ky][2] = a[ky * 3 + 0] + a[ky * 3 + 1];
    colc[ky][3] = a[ky * 3 + 2];
  }
  float* o = weff + (long)i * 16;
  #pragma unroll
  for (int px = 0; px < 2; ++px) {
    #pragma unroll
    for (int ix = 0; ix < 2; ++ix) {
      int j = px * 2 + ix;
      o[(0 * 2 + px) * 4 + 0 * 2 + ix] = colc[0][j];
      o[(0 * 2 + px) * 4 + 1 * 2 + ix] = colc[1][j] + colc[2][j];
      o[(1 * 2 + px) * 4 + 0 * 2 + ix] = colc[0][j] + colc[1][j];
      o[(1 * 2 + px) * 4 + 1 * 2 + ix] = colc[2][j];
    }
  }
}

// ---------------- stride-2 conv3x3 (d1,d2,d3), 2 px/thread ----------------
// JAX SAME stride2: pad_lo=0, pad_hi=1; out(o) reads rows 2o..2o+2.
template<int CIN, int COB, int NOCB, int CK, int OH, int OW>
__global__ __launch_bounds__(256) void convs2_k(
    const float* __restrict__ in, long in_nstride,
    const float* __restrict__ wgt, const float* __restrict__ bias,
    float* __restrict__ out, long out_nstride, int out_coff) {
  constexpr int TX = 32, TY = 16;
  constexpr int IW = 2 * OW, IH = 2 * OH;
  constexpr int LW = 2 * TX + 2;  // 66 (need 65)
  constexpr int LH = 2 * TY + 1;  // 33
  constexpr long OHW = (long)OH * OW;
  __shared__ float lds[CK][LH][LW];
  int tid = threadIdx.x;
  int ox = tid & 15, oy = tid >> 4;
  int z = blockIdx.z;
  int n = z / NOCB;
  int oc_base = (z % NOCB) * COB;
  int X0 = blockIdx.x * TX, Y0 = blockIdx.y * TY;
  int ix0 = 2 * X0, iy0 = 2 * Y0;

  float acc[COB][2];
  #pragma unroll
  for (int o = 0; o < COB; ++o) { acc[o][0] = 0.f; acc[o][1] = 0.f; }

  for (int c0 = 0; c0 < CIN; c0 += CK) {
    #pragma unroll
    for (int c = 0; c < CK; ++c) {
      const float* src = in + (long)n * in_nstride + (long)(c0 + c) * (IH * (long)IW);
      for (int i = tid; i < LH * LW; i += 256) {
        int r = i / LW, col = i - r * LW;
        int gy = iy0 + r, gx = ix0 + col;
        float v = 0.f;
        if (gy < IH && gx < IW) v = src[(long)gy * IW + gx];
        lds[c][r][col] = v;
      }
    }
    __syncthreads();
    #pragma unroll
    for (int c = 0; c < CK; ++c) {
      float v[2][9];
      #pragma unroll
      for (int i = 0; i < 2; ++i)
        #pragma unroll
        for (int ky = 0; ky < 3; ++ky)
          #pragma unroll
          for (int kx = 0; kx < 3; ++kx)
            v[i][ky * 3 + kx] = lds[c][2 * oy + ky][2 * (ox + 16 * i) + kx];
      #pragma unroll
      for (int oc = 0; oc < COB; ++oc) {
        const float* w9 = wgt + ((long)(oc_base + oc) * CIN + (c0 + c)) * 9;
        #pragma unroll
        for (int t = 0; t < 9; ++t) {
          acc[oc][0] = fmaf(w9[t], v[0][t], acc[oc][0]);
          acc[oc][1] = fmaf(w9[t], v[1][t], acc[oc][1]);
        }
      }
    }
    __syncthreads();
  }

  int oyg = Y0 + oy;
  #pragma unroll
  for (int i = 0; i < 2; ++i) {
    int oxg = X0 + ox + 16 * i;
    long pix = (long)oyg * OW + oxg;
    #pragma unroll
    for (int oc = 0; oc < COB; ++oc) {
      float x = acc[oc][i] + bias[oc_base + oc];
      x = x >= 0.f ? x : 0.2f * x;
      out[(long)n * out_nstride + (long)(out_coff + oc_base + oc) * OHW + pix] = x;
    }
  }
}

// ---------------- up2-folded stride-1 conv (u3,u2): 1 quad/thread ----------
template<int CIN, int COB, int NOCB, int CK, int SH>
__global__ __launch_bounds__(256) void convup_k(
    const float* __restrict__ in, long in_nstride,
    const float* __restrict__ weff, const float* __restrict__ bias,
    float* __restrict__ out, long out_nstride, int out_coff) {
  constexpr int SW = SH;
  constexpr int OW = 2 * SW;
  constexpr long OHW = (long)OW * OW;
  constexpr int LH = 18, LW = 18;
  __shared__ float lds[CK][LH][LW];
  int tid = threadIdx.x;
  int qx = tid & 15, qy = tid >> 4;
  int z = blockIdx.z;
  int n = z / NOCB;
  int oc_base = (z % NOCB) * COB;
  int QX0 = blockIdx.x * 16, QY0 = blockIdx.y * 16;

  float acc[COB][4];
  #pragma unroll
  for (int o = 0; o < COB; ++o)
    #pragma unroll
    for (int p = 0; p < 4; ++p) acc[o][p] = 0.f;

  for (int c0 = 0; c0 < CIN; c0 += CK) {
    for (int i = tid; i < CK * LH * LW; i += 256) {
      int c = i / (LH * LW);
      int rem = i - c * (LH * LW);
      int r = rem / LW, col = rem - r * LW;
      int gy = QY0 - 1 + r, gx = QX0 - 1 + col;
      float v = 0.f;
      if ((unsigned)gy < (unsigned)SH && (unsigned)gx < (unsigned)SW)
        v = in[(long)n * in_nstride + (long)(c0 + c) * (SH * (long)SW) + (long)gy * SW + gx];
      lds[c][r][col] = v;
    }
    __syncthreads();
    #pragma unroll
    for (int c = 0; c < CK; ++c) {
      float s[3][3];
      #pragma unroll
      for (int j = 0; j < 3; ++j)
        #pragma unroll
        for (int i = 0; i < 3; ++i)
          s[j][i] = lds[c][qy + j][qx + i];
      #pragma unroll
      for (int oc = 0; oc < COB; ++oc) {
        const float* W = weff + ((long)(oc_base + oc) * CIN + (c0 + c)) * 16;
        acc[oc][0] = fmaf(W[0], s[0][0], fmaf(W[1], s[0][1], fmaf(W[2], s[1][0], fmaf(W[3], s[1][1], acc[oc][0]))));
        acc[oc][1] = fmaf(W[4], s[0][1], fmaf(W[5], s[0][2], fmaf(W[6], s[1][1], fmaf(W[7], s[1][2], acc[oc][1]))));
        acc[oc][2] = fmaf(W[8], s[1][0], fmaf(W[9], s[1][1], fmaf(W[10], s[2][0], fmaf(W[11], s[2][1], acc[oc][2]))));
        acc[oc][3] = fmaf(W[12], s[1][1], fmaf(W[13], s[1][2], fmaf(W[14], s[2][1], fmaf(W[15], s[2][2], acc[oc][3]))));
      }
    }
    __syncthreads();
  }

  #pragma unroll
  for (int p = 0; p < 4; ++p) {
    int py = p >> 1, px = p & 1;
    int oyg = 2 * (QY0 + qy) + py;
    int oxg = 2 * (QX0 + qx) + px;
    long pix = (long)oyg * OW + oxg;
    #pragma unroll
    for (int oc = 0; oc < COB; ++oc) {
      float x = acc[oc][p] + bias[oc_base + oc];
      x = x >= 0.f ? x : 0.2f * x;
      out[(long)n * out_nstride + (long)(out_coff + oc_base + oc) * OHW + pix] = x;
    }
  }
}

// ---------------- u1: up2-folded conv 64->27 fused with final ----------------
// thread owns (qy,py,qx), computes px=0,1. acc[27][2].
__global__ __launch_bounds__(256) void convup_fuse_k(
    const float* __restrict__ in,         // d1cat (2,64,256,256)
    const float* __restrict__ weff,       // 27*64*16
    const float* __restrict__ bias,       // 27
    const float* __restrict__ m_in,       // (2,9,512,512)
    const float* __restrict__ alb_in,     // (2,3,512,512)
    float* __restrict__ fin_out) {
  constexpr int CK = 8, SH = 256, SW = 256;
  constexpr int LH = 10, LW = 18;
  __shared__ float lds[CK][LH][LW];
  int tid = threadIdx.x;
  int qx = tid & 15;
  int t2 = tid >> 4;
  int qy = t2 >> 1, py = t2 & 1;
  int n = blockIdx.z;
  int QX0 = blockIdx.x * 16, QY0 = blockIdx.y * 8;

  float acc[27][2];
  #pragma unroll
  for (int o = 0; o < 27; ++o) { acc[o][0] = 0.f; acc[o][1] = 0.f; }

  for (int c0 = 0; c0 < 64; c0 += CK) {
    for (int i = tid; i < CK * LH * LW; i += 256) {
      int c = i / (LH * LW);
      int rem = i - c * (LH * LW);
      int r = rem / LW, col = rem - r * LW;
      int gy = QY0 - 1 + r, gx = QX0 - 1 + col;
      float v = 0.f;
      if ((unsigned)gy < (unsigned)SH && (unsigned)gx < (unsigned)SW)
        v = in[(long)n * (64L * 65536) + (long)(c0 + c) * 65536 + (long)gy * SW + gx];
      lds[c][r][col] = v;
    }
    __syncthreads();
    #pragma unroll
    for (int c = 0; c < CK; ++c) {
      float s[2][3];
      #pragma unroll
      for (int j = 0; j < 2; ++j)
        #pragma unroll
        for (int i = 0; i < 3; ++i)
          s[j][i] = lds[c][qy + py + j][qx + i];
      #pragma unroll
      for (int oc = 0; oc < 27; ++oc) {
        const float* W = weff + ((long)oc * 64 + (c0 + c)) * 16 + py * 8;
        acc[oc][0] = fmaf(W[0], s[0][0], fmaf(W[1], s[0][1], fmaf(W[2], s[1][0], fmaf(W[3], s[1][1], acc[oc][0]))));
        acc[oc][1] = fmaf(W[4], s[0][1], fmaf(W[5], s[0][2], fmaf(W[6], s[1][1], fmaf(W[7], s[1][2], acc[oc][1]))));
      }
    }
    __syncthreads();
  }

  int oyg = 2 * (QY0 + qy) + py;
  #pragma unroll
  for (int px = 0; px < 2; ++px) {
    int oxg = 2 * (QX0 + qx) + px;
    long pix = (long)oyg * 512 + oxg;
    float s0 = 0.f, s1 = 0.f, s2 = 0.f;
    #pragma unroll
    for (int k = 0; k < 9; ++k) {
      float mk = m_in[((long)n * 9 + k) * HW + pix];
      s0 = fmaf(mk, acc[3 * k + 0][px] + bias[3 * k + 0], s0);
      s1 = fmaf(mk, acc[3 * k + 1][px] + bias[3 * k + 1], s1);
      s2 = fmaf(mk, acc[3 * k + 2][px] + bias[3 * k + 2], s2);
    }
    fin_out[((long)n * 3 + 0) * HW + pix] = alb_in[((long)n * 3 + 0) * HW + pix] * s0;
    fin_out[((long)n * 3 + 1) * HW + pix] = alb_in[((long)n * 3 + 1) * HW + pix] * s1;
    fin_out[((long)n * 3 + 2) * HW + pix] = alb_in[((long)n * 3 + 2) * HW + pix] * s2;
  }
}

// ---------------- launch ----------------
extern "C" void kernel_launch(void* const* d_in, const int* in_sizes, int n_in,
                              void* d_out, int out_size, void* d_ws, size_t ws_size,
                              hipStream_t stream) {
  const float* wi   = (const float*)d_in[0];
  const float* env  = (const float*)d_in[1];
  const float* uv   = (const float*)d_in[2];
  const float* ext  = (const float*)d_in[3];
  const float* atex = (const float*)d_in[4];
  const float* t1   = (const float*)d_in[5];
  const float* t2   = (const float*)d_in[6];
  const float* t3   = (const float*)d_in[7];
  const float* t4   = (const float*)d_in[8];
  const float* w_d1 = (const float*)d_in[9];
  const float* b_d1 = (const float*)d_in[10];
  const float* w_d2 = (const float*)d_in[11];
  const float* b_d2 = (const float*)d_in[12];
  const float* w_d3 = (const float*)d_in[13];
  const float* b_d3 = (const float*)d_in[14];
  const float* w_u3 = (const float*)d_in[15];
  const float* b_u3 = (const float*)d_in[16];
  const float* w_u2 = (const float*)d_in[17];
  const float* b_u2 = (const float*)d_in[18];
  const float* w_u1 = (const float*)d_in[19];
  const float* b_u1 = (const float*)d_in[20];
  float* out = (float*)d_out;
  float* ws  = (float*)d_ws;

  float* m_buf = ws + OFF_M;
  float* nt_buf = ws + OFF_NT;
  float* d2cat = ws + OFF_D2C;
  float* d3buf = ws + OFF_D3;
  float* d1cat = ws + OFF_D1C;
  float* we3 = ws + OFF_WE3;
  float* we2 = ws + OFF_WE2;
  float* we1 = ws + OFF_WE1;

  // stage A: bilinear samples + SH means + fwd_term + albedo outputs
  sample_sh_k<<<2048, 256, 0, stream>>>(wi, env, uv, ext, atex, t1, t2, t3, t4,
                                        m_buf, nt_buf, out);
  copy4_k<<<768, 256, 0, stream>>>((const float4*)atex, (float4*)out, 196608);

  // d1: nt(16,512^2) -> d1cat[32:64] (32,256^2)
  convs2_k<16, 32, 1, 4, 256, 256><<<dim3(8, 16, 2), 256, 0, stream>>>(
      nt_buf, 16L * HW, w_d1, b_d1, d1cat, 64L * 65536, 32);

  // expand up2-folded weights (region overlaps dead nt tail -> must be after d1)
  expand_w_k<<<32, 256, 0, stream>>>(w_u3, we3, 64 * 128);
  expand_w_k<<<16, 256, 0, stream>>>(w_u2, we2, 32 * 128);
  expand_w_k<<<7, 256, 0, stream>>>(w_u1, we1, 27 * 64);

  // d2: d1cat[32:64] -> d2cat[64:128] (64,128^2)
  convs2_k<32, 16, 4, 4, 128, 128><<<dim3(4, 8, 8), 256, 0, stream>>>(
      d1cat + 32L * 65536, 64L * 65536, w_d2, b_d2, d2cat, 128L * 16384, 64);

  // d3: d2cat[64:128] -> d3 (128,64^2)
  convs2_k<64, 8, 16, 4, 64, 64><<<dim3(2, 4, 32), 256, 0, stream>>>(
      d2cat + 64L * 16384, 128L * 16384, w_d3, b_d3, d3buf, 128L * 4096, 0);

  // u3: up2(d3) conv -> d2cat[0:64] (64,128^2)
  convup_k<128, 8, 8, 8, 64><<<dim3(4, 4, 16), 256, 0, stream>>>(
      d3buf, 128L * 4096, we3, b_u3, d2cat, 128L * 16384, 0);

  // u2: up2(d2cat) conv -> d1cat[0:32] (32,256^2)
  convup_k<128, 16, 2, 8, 128><<<dim3(8, 8, 4), 256, 0, stream>>>(
      d2cat, 128L * 16384, we2, b_u2, d1cat, 64L * 65536, 0);

  // u1: up2(d1cat) conv 64->27 fused with final-dot
  convup_fuse_k<<<dim3(16, 32, 2), 256, 0, stream>>>(
      d1cat, we1, b_u1, m_buf, out + OUT_ALB, out + OUT_FINAL);
}

// Round 3
// 1676.586 us; speedup vs baseline: 1.9113x; 1.4858x over previous
//
#include <hip/hip_runtime.h>

// ---------------- constants / layout ----------------
constexpr int HW = 512 * 512; // 262144

// d_out layout (floats)
constexpr long OUT_FINAL = 786432;
constexpr long OUT_FWD   = 2359296;
constexpr long OUT_ALB   = 3932160;

// workspace layout (floats)
constexpr long OFF_M   = 0;                  // m: (2,9,512,512)
constexpr long OFF_NT  = 4718592;            // nt:(2,16,512,512)  dies after d1
constexpr long OFF_D2C = 4718592;            // d2cat:(2,128,128,128) aliases nt
constexpr long OFF_D3  = 8912896;            // d3:(2,128,64,64)
constexpr long OFF_WE3 = 9961472;            // weff u3: 64*128*16 = 131072  (aliases dead nt tail)
constexpr long OFF_WE2 = 10092544;           // weff u2: 32*128*16 = 65536
constexpr long OFF_WE1 = 10158080;           // weff u1: 27*64*16  = 27648
constexpr long OFF_D1C = 13107200;           // d1cat:(2,64,256,256)

// ---------------- bilinear sampling ----------------
__device__ __forceinline__ void bl_setup(float u, float v, int T,
                                         int& x0, int& y0, float& wx, float& wy) {
  float px = u * (float)(T - 1);
  float py = v * (float)(T - 1);
  int xi = (int)floorf(px);
  int yi = (int)floorf(py);
  xi = xi < 0 ? 0 : (xi > T - 2 ? T - 2 : xi);
  yi = yi < 0 ? 0 : (yi > T - 2 ? T - 2 : yi);
  wx = px - (float)xi;
  wy = py - (float)yi;
  x0 = xi; y0 = yi;
}

template<int C, int T>
__device__ __forceinline__ void sample_acc(const float* __restrict__ tex,
                                           float u, float v, float* o) {
  int x0, y0; float wx, wy;
  bl_setup(u, v, T, x0, y0, wx, wy);
  float w00 = (1.f - wx) * (1.f - wy), w01 = wx * (1.f - wy);
  float w10 = (1.f - wx) * wy,         w11 = wx * wy;
  const float* b = tex + y0 * T + x0;
  #pragma unroll
  for (int c = 0; c < C; ++c) {
    o[c] += b[0] * w00 + b[1] * w01 + b[T] * w10 + b[T + 1] * w11;
    b += T * T;
  }
}

// ---------------- stage A: sample + SH reduce ----------------
__global__ __launch_bounds__(256) void sample_sh_k(
    const float* __restrict__ wi, const float* __restrict__ env,
    const float* __restrict__ uv, const float* __restrict__ ext,
    const float* __restrict__ atex,
    const float* __restrict__ t1, const float* __restrict__ t2,
    const float* __restrict__ t3, const float* __restrict__ t4,
    float* __restrict__ m_out, float* __restrict__ nt_out,
    float* __restrict__ dout) {
  int idx = blockIdx.x * 256 + threadIdx.x;   // 0 .. 524287
  int n = idx >> 18;
  int p = idx & (HW - 1);

  float2 uvv = reinterpret_cast<const float2*>(uv)[idx];
  float u = uvv.x, v = uvv.y;

  float alb[3] = {0.f, 0.f, 0.f};
  sample_acc<3, 512>(atex, u, v, alb);

  float nt[16];
  #pragma unroll
  for (int c = 0; c < 16; ++c) nt[c] = 0.f;
  sample_acc<16, 512>(t1, u, v, nt);
  sample_acc<16, 256>(t2, u, v, nt);
  sample_acc<16, 128>(t3, u, v, nt);
  sample_acc<16, 64>(t4, u, v, nt);

  const float C0f = 0.28209479177387814f, C1f = 0.4886025119029199f;
  const float C2f = 1.0925484305920792f, C20f = 0.31539156525252005f;
  const float C22f = 0.5462742152960396f;
  const float SQ = 0.70710678118654752f;

  float ex = ext[n * 3 + 0], ey = ext[n * 3 + 1], ez = ext[n * 3 + 2];
  float basis[9];
  basis[0] = C0f;
  basis[1] = ey * C1f * SQ;
  basis[2] = ez * C1f;
  basis[3] = -ex * C1f * SQ;
  basis[4] = ex * ey * C2f * 0.5f * SQ;
  basis[5] = ey * ez * C2f * SQ;
  basis[6] = (3.f * ez * ez - 1.f) * C20f;
  basis[7] = -ez * ex * C2f * SQ;
  basis[8] = (ex * ex - ez * ez) * C2f * 0.5f * SQ;
  #pragma unroll
  for (int j = 0; j < 9; ++j) nt[3 + j] *= basis[j];

  float ms[8];
  #pragma unroll
  for (int j = 0; j < 8; ++j) ms[j] = 0.f;
  float es[3] = {0.f, 0.f, 0.f};

  const float* wb = wi + ((long)n * 20) * HW + p;
  const float* eb = env + ((long)n * 30) * HW + p;
  #pragma unroll
  for (int ss = 0; ss < 10; ++ss) {
    float th = wb[(long)ss * HW];
    float ph = wb[(long)(10 + ss) * HW];
    float st, ct, sp, cp;
    sincosf(th, &st, &ct);
    sincosf(ph, &sp, &cp);
    float x = st * cp, y = st * sp, z = ct;
    ms[0] += y; ms[1] += z; ms[2] += x;
    ms[3] += x * y; ms[4] += y * z;
    ms[5] += 3.f * z * z - 1.f;
    ms[6] += x * z; ms[7] += x * x - y * y;
    es[0] += eb[(long)ss * HW];
    es[1] += eb[(long)(10 + ss) * HW];
    es[2] += eb[(long)(20 + ss) * HW];
  }

  float m[9];
  m[0] = C0f;
  m[1] = C1f * ms[0] * 0.1f; m[2] = C1f * ms[1] * 0.1f; m[3] = C1f * ms[2] * 0.1f;
  m[4] = C2f * ms[3] * 0.1f; m[5] = C2f * ms[4] * 0.1f; m[6] = C20f * ms[5] * 0.1f;
  m[7] = C2f * ms[6] * 0.1f; m[8] = C22f * ms[7] * 0.1f;

  #pragma unroll
  for (int k = 0; k < 9; ++k) m_out[((long)n * 9 + k) * HW + p] = m[k];
  #pragma unroll
  for (int c = 0; c < 16; ++c) nt_out[((long)n * 16 + c) * HW + p] = nt[c];
  #pragma unroll
  for (int c = 0; c < 3; ++c) {
    dout[OUT_FWD + ((long)n * 3 + c) * HW + p] = alb[c] * es[c] * 0.1f;
    dout[OUT_ALB + ((long)n * 3 + c) * HW + p] = alb[c];
  }
}

// ---------------- albedo_tex copy ----------------
__global__ __launch_bounds__(256) void copy4_k(const float4* __restrict__ s,
                                               float4* __restrict__ d, int n) {
  int i = blockIdx.x * 256 + threadIdx.x;
  if (i < n) d[i] = s[i];
}

// ---------------- up2-folded weight expansion ----------------
__global__ __launch_bounds__(256) void expand_w_k(const float* __restrict__ w,
                                                  float* __restrict__ weff,
                                                  int total) {
  int i = blockIdx.x * 256 + threadIdx.x;
  if (i >= total) return;
  float a[9];
  #pragma unroll
  for (int t = 0; t < 9; ++t) a[t] = w[(long)i * 9 + t];
  float colc[3][4]; // [ky][px*2+ix]
  #pragma unroll
  for (int ky = 0; ky < 3; ++ky) {
    colc[ky][0] = a[ky * 3 + 0];
    colc[ky][1] = a[ky * 3 + 1] + a[ky * 3 + 2];
    colc[ky][2] = a[ky * 3 + 0] + a[ky * 3 + 1];
    colc[ky][3] = a[ky * 3 + 2];
  }
  float* o = weff + (long)i * 16;
  #pragma unroll
  for (int px = 0; px < 2; ++px) {
    #pragma unroll
    for (int ix = 0; ix < 2; ++ix) {
      int j = px * 2 + ix;
      o[(0 * 2 + px) * 4 + 0 * 2 + ix] = colc[0][j];
      o[(0 * 2 + px) * 4 + 1 * 2 + ix] = colc[1][j] + colc[2][j];
      o[(1 * 2 + px) * 4 + 0 * 2 + ix] = colc[0][j] + colc[1][j];
      o[(1 * 2 + px) * 4 + 1 * 2 + ix] = colc[2][j];
    }
  }
}

// ---------------- stride-2 conv3x3 (d1,d2,d3), 2 px/thread ----------------
template<int CIN, int COB, int NOCB, int CK, int OH, int OW>
__global__ __launch_bounds__(256, 4) void convs2_k(
    const float* __restrict__ in, long in_nstride,
    const float* __restrict__ wgt, const float* __restrict__ bias,
    float* __restrict__ out, long out_nstride, int out_coff) {
  constexpr int TX = 32, TY = 16;
  constexpr int IW = 2 * OW, IH = 2 * OH;
  constexpr int LW = 2 * TX + 2;  // 66
  constexpr int LH = 2 * TY + 1;  // 33
  constexpr long OHW = (long)OH * OW;
  __shared__ float lds[CK][LH][LW];
  int tid = threadIdx.x;
  int ox = tid & 15, oy = tid >> 4;
  int z = blockIdx.z;
  int n = z / NOCB;
  int oc_base = (z % NOCB) * COB;
  int X0 = blockIdx.x * TX, Y0 = blockIdx.y * TY;
  int ix0 = 2 * X0, iy0 = 2 * Y0;

  float acc[COB][2];
  #pragma unroll
  for (int o = 0; o < COB; ++o) { acc[o][0] = 0.f; acc[o][1] = 0.f; }

  for (int c0 = 0; c0 < CIN; c0 += CK) {
    #pragma unroll
    for (int c = 0; c < CK; ++c) {
      const float* src = in + (long)n * in_nstride + (long)(c0 + c) * (IH * (long)IW);
      for (int i = tid; i < LH * LW; i += 256) {
        int r = i / LW, col = i - r * LW;
        int gy = iy0 + r, gx = ix0 + col;
        float v = 0.f;
        if (gy < IH && gx < IW) v = src[(long)gy * IW + gx];
        lds[c][r][col] = v;
      }
    }
    __syncthreads();
    #pragma unroll
    for (int c = 0; c < CK; ++c) {
      float v[2][9];
      #pragma unroll
      for (int i = 0; i < 2; ++i)
        #pragma unroll
        for (int ky = 0; ky < 3; ++ky)
          #pragma unroll
          for (int kx = 0; kx < 3; ++kx)
            v[i][ky * 3 + kx] = lds[c][2 * oy + ky][2 * (ox + 16 * i) + kx];
      #pragma unroll
      for (int oc = 0; oc < COB; ++oc) {
        const float* w9 = wgt + ((long)(oc_base + oc) * CIN + (c0 + c)) * 9;
        #pragma unroll
        for (int t = 0; t < 9; ++t) {
          acc[oc][0] = fmaf(w9[t], v[0][t], acc[oc][0]);
          acc[oc][1] = fmaf(w9[t], v[1][t], acc[oc][1]);
        }
      }
    }
    __syncthreads();
  }

  int oyg = Y0 + oy;
  #pragma unroll
  for (int i = 0; i < 2; ++i) {
    int oxg = X0 + ox + 16 * i;
    long pix = (long)oyg * OW + oxg;
    #pragma unroll
    for (int oc = 0; oc < COB; ++oc) {
      float x = acc[oc][i] + bias[oc_base + oc];
      x = x >= 0.f ? x : 0.2f * x;
      out[(long)n * out_nstride + (long)(out_coff + oc_base + oc) * OHW + pix] = x;
    }
  }
}

// ---------------- up2-folded stride-1 conv (u3,u2): 1 quad/thread ----------
// LDS row stride 40 (== 8 mod 32) -> 2-way bank aliasing only (free).
template<int CIN, int COB, int NOCB, int CK, int SH>
__global__ __launch_bounds__(256, 4) void convup_k(
    const float* __restrict__ in, long in_nstride,
    const float* __restrict__ weff, const float* __restrict__ bias,
    float* __restrict__ out, long out_nstride, int out_coff) {
  constexpr int SW = SH;
  constexpr int OW = 2 * SW;
  constexpr long OHW = (long)OW * OW;
  constexpr int LH = 18, LW = 40;   // need 18 cols, pad to 40
  __shared__ float lds[CK][LH][LW];
  int tid = threadIdx.x;
  int qx = tid & 15, qy = tid >> 4;
  int z = blockIdx.z;
  int n = z / NOCB;
  int oc_base = (z % NOCB) * COB;
  int QX0 = blockIdx.x * 16, QY0 = blockIdx.y * 16;

  float acc[COB][4];
  #pragma unroll
  for (int o = 0; o < COB; ++o)
    #pragma unroll
    for (int p = 0; p < 4; ++p) acc[o][p] = 0.f;

  for (int c0 = 0; c0 < CIN; c0 += CK) {
    for (int i = tid; i < CK * LH * 18; i += 256) {
      int c = i / (LH * 18);
      int rem = i - c * (LH * 18);
      int r = rem / 18, col = rem - r * 18;
      int gy = QY0 - 1 + r, gx = QX0 - 1 + col;
      float v = 0.f;
      if ((unsigned)gy < (unsigned)SH && (unsigned)gx < (unsigned)SW)
        v = in[(long)n * in_nstride + (long)(c0 + c) * (SH * (long)SW) + (long)gy * SW + gx];
      lds[c][r][col] = v;
    }
    __syncthreads();
    #pragma unroll
    for (int c = 0; c < CK; ++c) {
      float s[3][3];
      #pragma unroll
      for (int j = 0; j < 3; ++j)
        #pragma unroll
        for (int i = 0; i < 3; ++i)
          s[j][i] = lds[c][qy + j][qx + i];
      #pragma unroll
      for (int oc = 0; oc < COB; ++oc) {
        const float* W = weff + ((long)(oc_base + oc) * CIN + (c0 + c)) * 16;
        acc[oc][0] = fmaf(W[0], s[0][0], fmaf(W[1], s[0][1], fmaf(W[2], s[1][0], fmaf(W[3], s[1][1], acc[oc][0]))));
        acc[oc][1] = fmaf(W[4], s[0][1], fmaf(W[5], s[0][2], fmaf(W[6], s[1][1], fmaf(W[7], s[1][2], acc[oc][1]))));
        acc[oc][2] = fmaf(W[8], s[1][0], fmaf(W[9], s[1][1], fmaf(W[10], s[2][0], fmaf(W[11], s[2][1], acc[oc][2]))));
        acc[oc][3] = fmaf(W[12], s[1][1], fmaf(W[13], s[1][2], fmaf(W[14], s[2][1], fmaf(W[15], s[2][2], acc[oc][3]))));
      }
    }
    __syncthreads();
  }

  #pragma unroll
  for (int p = 0; p < 4; ++p) {
    int py = p >> 1, px = p & 1;
    int oyg = 2 * (QY0 + qy) + py;
    int oxg = 2 * (QX0 + qx) + px;
    long pix = (long)oyg * OW + oxg;
    #pragma unroll
    for (int oc = 0; oc < COB; ++oc) {
      float x = acc[oc][p] + bias[oc_base + oc];
      x = x >= 0.f ? x : 0.2f * x;
      out[(long)n * out_nstride + (long)(out_coff + oc_base + oc) * OHW + pix] = x;
    }
  }
}

// ---------------- u1: up2-folded conv 64->27 fused with final ----------------
// py is WAVE-uniform (wave = tid>>6, py = wave&1, forced to SGPR via
// readfirstlane) so weight loads take the SMEM path (s_load_dwordx8 shared
// by 64 lanes) instead of per-lane vector loads.
__global__ __launch_bounds__(256, 4) void convup_fuse_k(
    const float* __restrict__ in,         // d1cat (2,64,256,256)
    const float* __restrict__ weff,       // 27*64*16
    const float* __restrict__ bias,       // 27
    const float* __restrict__ m_in,       // (2,9,512,512)
    const float* __restrict__ alb_in,     // (2,3,512,512)
    float* __restrict__ fin_out) {
  constexpr int CK = 8, SH = 256, SW = 256;
  constexpr int LH = 10, LW = 40;   // need 18 cols, pad to 40
  __shared__ float lds[CK][LH][LW];
  int tid = threadIdx.x;
  int qx = tid & 15;
  int waveu = __builtin_amdgcn_readfirstlane(tid >> 6);   // 0..3, wave-uniform SGPR
  int py = waveu & 1;                                     // SGPR
  int qy = ((waveu >> 1) << 2) + ((tid >> 4) & 3);        // 0..7
  int n = blockIdx.z;
  int QX0 = blockIdx.x * 16, QY0 = blockIdx.y * 8;

  float acc[27][2];
  #pragma unroll
  for (int o = 0; o < 27; ++o) { acc[o][0] = 0.f; acc[o][1] = 0.f; }

  for (int c0 = 0; c0 < 64; c0 += CK) {
    for (int i = tid; i < CK * LH * 18; i += 256) {
      int c = i / (LH * 18);
      int rem = i - c * (LH * 18);
      int r = rem / 18, col = rem - r * 18;
      int gy = QY0 - 1 + r, gx = QX0 - 1 + col;
      float v = 0.f;
      if ((unsigned)gy < (unsigned)SH && (unsigned)gx < (unsigned)SW)
        v = in[(long)n * (64L * 65536) + (long)(c0 + c) * 65536 + (long)gy * SW + gx];
      lds[c][r][col] = v;
    }
    __syncthreads();
    #pragma unroll
    for (int c = 0; c < CK; ++c) {
      float s[2][3];
      #pragma unroll
      for (int j = 0; j < 2; ++j)
        #pragma unroll
        for (int i = 0; i < 3; ++i)
          s[j][i] = lds[c][qy + py + j][qx + i];
      #pragma unroll
      for (int oc = 0; oc < 27; ++oc) {
        const float* W = weff + ((long)oc * 64 + (c0 + c)) * 16 + py * 8;
        acc[oc][0] = fmaf(W[0], s[0][0], fmaf(W[1], s[0][1], fmaf(W[2], s[1][0], fmaf(W[3], s[1][1], acc[oc][0]))));
        acc[oc][1] = fmaf(W[4], s[0][1], fmaf(W[5], s[0][2], fmaf(W[6], s[1][1], fmaf(W[7], s[1][2], acc[oc][1]))));
      }
    }
    __syncthreads();
  }

  int oyg = 2 * (QY0 + qy) + py;
  #pragma unroll
  for (int px = 0; px < 2; ++px) {
    int oxg = 2 * (QX0 + qx) + px;
    long pix = (long)oyg * 512 + oxg;
    float s0 = 0.f, s1 = 0.f, s2 = 0.f;
    #pragma unroll
    for (int k = 0; k < 9; ++k) {
      float mk = m_in[((long)n * 9 + k) * HW + pix];
      s0 = fmaf(mk, acc[3 * k + 0][px] + bias[3 * k + 0], s0);
      s1 = fmaf(mk, acc[3 * k + 1][px] + bias[3 * k + 1], s1);
      s2 = fmaf(mk, acc[3 * k + 2][px] + bias[3 * k + 2], s2);
    }
    fin_out[((long)n * 3 + 0) * HW + pix] = alb_in[((long)n * 3 + 0) * HW + pix] * s0;
    fin_out[((long)n * 3 + 1) * HW + pix] = alb_in[((long)n * 3 + 1) * HW + pix] * s1;
    fin_out[((long)n * 3 + 2) * HW + pix] = alb_in[((long)n * 3 + 2) * HW + pix] * s2;
  }
}

// ---------------- launch ----------------
extern "C" void kernel_launch(void* const* d_in, const int* in_sizes, int n_in,
                              void* d_out, int out_size, void* d_ws, size_t ws_size,
                              hipStream_t stream) {
  const float* wi   = (const float*)d_in[0];
  const float* env  = (const float*)d_in[1];
  const float* uv   = (const float*)d_in[2];
  const float* ext  = (const float*)d_in[3];
  const float* atex = (const float*)d_in[4];
  const float* t1   = (const float*)d_in[5];
  const float* t2   = (const float*)d_in[6];
  const float* t3   = (const float*)d_in[7];
  const float* t4   = (const float*)d_in[8];
  const float* w_d1 = (const float*)d_in[9];
  const float* b_d1 = (const float*)d_in[10];
  const float* w_d2 = (const float*)d_in[11];
  const float* b_d2 = (const float*)d_in[12];
  const float* w_d3 = (const float*)d_in[13];
  const float* b_d3 = (const float*)d_in[14];
  const float* w_u3 = (const float*)d_in[15];
  const float* b_u3 = (const float*)d_in[16];
  const float* w_u2 = (const float*)d_in[17];
  const float* b_u2 = (const float*)d_in[18];
  const float* w_u1 = (const float*)d_in[19];
  const float* b_u1 = (const float*)d_in[20];
  float* out = (float*)d_out;
  float* ws  = (float*)d_ws;

  float* m_buf = ws + OFF_M;
  float* nt_buf = ws + OFF_NT;
  float* d2cat = ws + OFF_D2C;
  float* d3buf = ws + OFF_D3;
  float* d1cat = ws + OFF_D1C;
  float* we3 = ws + OFF_WE3;
  float* we2 = ws + OFF_WE2;
  float* we1 = ws + OFF_WE1;

  // stage A
  sample_sh_k<<<2048, 256, 0, stream>>>(wi, env, uv, ext, atex, t1, t2, t3, t4,
                                        m_buf, nt_buf, out);
  copy4_k<<<768, 256, 0, stream>>>((const float4*)atex, (float4*)out, 196608);

  // d1: nt(16,512^2) -> d1cat[32:64] (32,256^2)  [512 blocks]
  convs2_k<16, 16, 2, 4, 256, 256><<<dim3(8, 16, 4), 256, 0, stream>>>(
      nt_buf, 16L * HW, w_d1, b_d1, d1cat, 64L * 65536, 32);

  // expand up2-folded weights (aliases dead nt tail -> must launch after d1)
  expand_w_k<<<32, 256, 0, stream>>>(w_u3, we3, 64 * 128);
  expand_w_k<<<16, 256, 0, stream>>>(w_u2, we2, 32 * 128);
  expand_w_k<<<7, 256, 0, stream>>>(w_u1, we1, 27 * 64);

  // d2: d1cat[32:64] -> d2cat[64:128] (64,128^2)  [512 blocks]
  convs2_k<32, 8, 8, 4, 128, 128><<<dim3(4, 8, 16), 256, 0, stream>>>(
      d1cat + 32L * 65536, 64L * 65536, w_d2, b_d2, d2cat, 128L * 16384, 64);

  // d3: d2cat[64:128] -> d3 (128,64^2)  [512 blocks]
  convs2_k<64, 4, 32, 4, 64, 64><<<dim3(2, 4, 64), 256, 0, stream>>>(
      d2cat + 64L * 16384, 128L * 16384, w_d3, b_d3, d3buf, 128L * 4096, 0);

  // u3: up2(d3) conv -> d2cat[0:64] (64,128^2)  [512 blocks]
  convup_k<128, 4, 16, 8, 64><<<dim3(4, 4, 32), 256, 0, stream>>>(
      d3buf, 128L * 4096, we3, b_u3, d2cat, 128L * 16384, 0);

  // u2: up2(d2cat) conv -> d1cat[0:32] (32,256^2)  [512 blocks]
  convup_k<128, 8, 4, 8, 128><<<dim3(8, 8, 8), 256, 0, stream>>>(
      d2cat, 128L * 16384, we2, b_u2, d1cat, 64L * 65536, 0);

  // u1: up2(d1cat) conv 64->27 fused with final-dot  [1024 blocks]
  convup_fuse_k<<<dim3(16, 32, 2), 256, 0, stream>>>(
      d1cat, we1, b_u1, m_buf, out + OUT_ALB, out + OUT_FINAL);
}

// Round 4
// 1375.031 us; speedup vs baseline: 2.3305x; 1.2193x over previous
//
#include <hip/hip_runtime.h>

// ---------------- constants / layout ----------------
constexpr int HW = 512 * 512; // 262144

// d_out layout (floats)
constexpr long OUT_FINAL = 786432;
constexpr long OUT_FWD   = 2359296;
constexpr long OUT_ALB   = 3932160;

// workspace layout (floats)
constexpr long OFF_M   = 0;                  // m: (2,9,512,512)
constexpr long OFF_NT  = 4718592;            // nt:(2,16,512,512)  dies after d1
constexpr long OFF_D2C = 4718592;            // d2cat:(2,128,128,128) aliases nt
constexpr long OFF_D3  = 8912896;            // d3:(2,128,64,64)
constexpr long OFF_WE3 = 9961472;            // weff u3 (aliases dead nt tail)
constexpr long OFF_WE2 = 10092544;           // weff u2
constexpr long OFF_WE1 = 10158080;           // weff u1
constexpr long OFF_D1C = 13107200;           // d1cat:(2,64,256,256)
// interleaved textures alias the d1cat region (dead until d1 writes it):
constexpr long OFF_TA  = OFF_D1C;            // (512,512,4)  = 1,048,576
constexpr long OFF_T1  = OFF_D1C + 1048576;  // (512,512,16) = 4,194,304
constexpr long OFF_T2  = OFF_D1C + 5242880;  // (256,256,16) = 1,048,576
constexpr long OFF_T3  = OFF_D1C + 6291456;  // (128,128,16) = 262,144
constexpr long OFF_T4  = OFF_D1C + 6553600;  // (64,64,16)   = 65,536

// ---------------- bilinear helpers ----------------
__device__ __forceinline__ void bl_setup(float u, float v, int T,
                                         int& x0, int& y0, float& wx, float& wy) {
  float px = u * (float)(T - 1);
  float py = v * (float)(T - 1);
  int xi = (int)floorf(px);
  int yi = (int)floorf(py);
  xi = xi < 0 ? 0 : (xi > T - 2 ? T - 2 : xi);
  yi = yi < 0 ? 0 : (yi > T - 2 ? T - 2 : yi);
  wx = px - (float)xi;
  wy = py - (float)yi;
  x0 = xi; y0 = yi;
}

// interleaved (H,W,16) bilinear accumulate, 16 float4 loads
template<int T>
__device__ __forceinline__ void sample16i(const float* __restrict__ tex,
                                          float u, float v, float* nt) {
  int x0, y0; float wx, wy;
  bl_setup(u, v, T, x0, y0, wx, wy);
  float w00 = (1.f - wx) * (1.f - wy), w01 = wx * (1.f - wy);
  float w10 = (1.f - wx) * wy,         w11 = wx * wy;
  const float4* b = (const float4*)tex;
  int i00 = (y0 * T + x0) * 4;
  #pragma unroll
  for (int g = 0; g < 4; ++g) {
    float4 v00 = b[i00 + g];
    float4 v01 = b[i00 + 4 + g];
    float4 v10 = b[i00 + T * 4 + g];
    float4 v11 = b[i00 + T * 4 + 4 + g];
    nt[4 * g + 0] += v00.x * w00 + v01.x * w01 + v10.x * w10 + v11.x * w11;
    nt[4 * g + 1] += v00.y * w00 + v01.y * w01 + v10.y * w10 + v11.y * w11;
    nt[4 * g + 2] += v00.z * w00 + v01.z * w01 + v10.z * w10 + v11.z * w11;
    nt[4 * g + 3] += v00.w * w00 + v01.w * w01 + v10.w * w10 + v11.w * w11;
  }
}

// ---------------- texture transpose: (C,H,W) -> (H,W,CP) ----------------
template<int NPIX>
__global__ __launch_bounds__(256) void transpose16_k(const float* __restrict__ src,
                                                     float* __restrict__ dst) {
  int p = blockIdx.x * 256 + threadIdx.x;
  if (p >= NPIX) return;
  float v[16];
  #pragma unroll
  for (int c = 0; c < 16; ++c) v[c] = src[(long)c * NPIX + p];
  float4* d = (float4*)(dst + (long)p * 16);
  d[0] = make_float4(v[0], v[1], v[2], v[3]);
  d[1] = make_float4(v[4], v[5], v[6], v[7]);
  d[2] = make_float4(v[8], v[9], v[10], v[11]);
  d[3] = make_float4(v[12], v[13], v[14], v[15]);
}

__global__ __launch_bounds__(256) void transpose3_k(const float* __restrict__ src,
                                                    float* __restrict__ dst) {
  int p = blockIdx.x * 256 + threadIdx.x;
  if (p >= HW) return;
  ((float4*)dst)[p] = make_float4(src[p], src[HW + p], src[2 * HW + p], 0.f);
}

// ---------------- stage A1: uv-gather of all textures ----------------
__global__ __launch_bounds__(256, 4) void sample_tex_k(
    const float* __restrict__ uv, const float* __restrict__ ext,
    const float* __restrict__ TA, const float* __restrict__ T1,
    const float* __restrict__ T2, const float* __restrict__ T3,
    const float* __restrict__ T4,
    float* __restrict__ nt_out, float* __restrict__ alb_out) {
  int idx = blockIdx.x * 256 + threadIdx.x;
  int n = idx >> 18;
  int p = idx & (HW - 1);
  float2 uvv = reinterpret_cast<const float2*>(uv)[idx];
  float u = uvv.x, v = uvv.y;

  // albedo from (512,512,4)
  int x0, y0; float wx, wy;
  bl_setup(u, v, 512, x0, y0, wx, wy);
  float w00 = (1.f - wx) * (1.f - wy), w01 = wx * (1.f - wy);
  float w10 = (1.f - wx) * wy,         w11 = wx * wy;
  const float4* A = (const float4*)TA;
  float4 a00 = A[y0 * 512 + x0], a01 = A[y0 * 512 + x0 + 1];
  float4 a10 = A[(y0 + 1) * 512 + x0], a11 = A[(y0 + 1) * 512 + x0 + 1];
  float alb[3];
  alb[0] = a00.x * w00 + a01.x * w01 + a10.x * w10 + a11.x * w11;
  alb[1] = a00.y * w00 + a01.y * w01 + a10.y * w10 + a11.y * w11;
  alb[2] = a00.z * w00 + a01.z * w01 + a10.z * w10 + a11.z * w11;

  float nt[16];
  #pragma unroll
  for (int c = 0; c < 16; ++c) nt[c] = 0.f;
  sample16i<512>(T1, u, v, nt);
  sample16i<256>(T2, u, v, nt);
  sample16i<128>(T3, u, v, nt);
  sample16i<64>(T4, u, v, nt);

  const float C0f = 0.28209479177387814f, C1f = 0.4886025119029199f;
  const float C2f = 1.0925484305920792f, C20f = 0.31539156525252005f;
  const float SQ = 0.70710678118654752f;
  float ex = ext[n * 3 + 0], ey = ext[n * 3 + 1], ez = ext[n * 3 + 2];
  float basis[9];
  basis[0] = C0f;
  basis[1] = ey * C1f * SQ;
  basis[2] = ez * C1f;
  basis[3] = -ex * C1f * SQ;
  basis[4] = ex * ey * C2f * 0.5f * SQ;
  basis[5] = ey * ez * C2f * SQ;
  basis[6] = (3.f * ez * ez - 1.f) * C20f;
  basis[7] = -ez * ex * C2f * SQ;
  basis[8] = (ex * ex - ez * ez) * C2f * 0.5f * SQ;
  #pragma unroll
  for (int j = 0; j < 9; ++j) nt[3 + j] *= basis[j];

  #pragma unroll
  for (int c = 0; c < 16; ++c)
    __builtin_nontemporal_store(nt[c], &nt_out[((long)n * 16 + c) * HW + p]);
  #pragma unroll
  for (int c = 0; c < 3; ++c)
    __builtin_nontemporal_store(alb[c], &alb_out[((long)n * 3 + c) * HW + p]);
}

// ---------------- stage A2: SH/env streaming reduce ----------------
__global__ __launch_bounds__(256, 4) void sh_env_k(
    const float* __restrict__ wi, const float* __restrict__ env,
    const float* __restrict__ alb_in,
    float* __restrict__ m_out, float* __restrict__ fwd_out) {
  int idx = blockIdx.x * 256 + threadIdx.x;
  int n = idx >> 18;
  int p = idx & (HW - 1);

  const float C0f = 0.28209479177387814f, C1f = 0.4886025119029199f;
  const float C2f = 1.0925484305920792f, C20f = 0.31539156525252005f;
  const float C22f = 0.5462742152960396f;

  float ms[8];
  #pragma unroll
  for (int j = 0; j < 8; ++j) ms[j] = 0.f;
  float es[3] = {0.f, 0.f, 0.f};

  const float* wb = wi + ((long)n * 20) * HW + p;
  const float* eb = env + ((long)n * 30) * HW + p;
  #pragma unroll
  for (int ss = 0; ss < 10; ++ss) {
    float th = __builtin_nontemporal_load(&wb[(long)ss * HW]);
    float ph = __builtin_nontemporal_load(&wb[(long)(10 + ss) * HW]);
    float st, ct, sp, cp;
    sincosf(th, &st, &ct);
    sincosf(ph, &sp, &cp);
    float x = st * cp, y = st * sp, z = ct;
    ms[0] += y; ms[1] += z; ms[2] += x;
    ms[3] += x * y; ms[4] += y * z;
    ms[5] += 3.f * z * z - 1.f;
    ms[6] += x * z; ms[7] += x * x - y * y;
    es[0] += __builtin_nontemporal_load(&eb[(long)ss * HW]);
    es[1] += __builtin_nontemporal_load(&eb[(long)(10 + ss) * HW]);
    es[2] += __builtin_nontemporal_load(&eb[(long)(20 + ss) * HW]);
  }

  float m[9];
  m[0] = C0f;
  m[1] = C1f * ms[0] * 0.1f; m[2] = C1f * ms[1] * 0.1f; m[3] = C1f * ms[2] * 0.1f;
  m[4] = C2f * ms[3] * 0.1f; m[5] = C2f * ms[4] * 0.1f; m[6] = C20f * ms[5] * 0.1f;
  m[7] = C2f * ms[6] * 0.1f; m[8] = C22f * ms[7] * 0.1f;

  #pragma unroll
  for (int k = 0; k < 9; ++k)
    __builtin_nontemporal_store(m[k], &m_out[((long)n * 9 + k) * HW + p]);
  #pragma unroll
  for (int c = 0; c < 3; ++c) {
    float a = alb_in[((long)n * 3 + c) * HW + p];
    __builtin_nontemporal_store(a * es[c] * 0.1f, &fwd_out[((long)n * 3 + c) * HW + p]);
  }
}

// ---------------- albedo_tex copy ----------------
__global__ __launch_bounds__(256) void copy4_k(const float4* __restrict__ s,
                                               float4* __restrict__ d, int n) {
  int i = blockIdx.x * 256 + threadIdx.x;
  if (i < n) d[i] = s[i];
}

// ---------------- up2-folded weight expansion ----------------
__global__ __launch_bounds__(256) void expand_w_k(const float* __restrict__ w,
                                                  float* __restrict__ weff,
                                                  int total) {
  int i = blockIdx.x * 256 + threadIdx.x;
  if (i >= total) return;
  float a[9];
  #pragma unroll
  for (int t = 0; t < 9; ++t) a[t] = w[(long)i * 9 + t];
  float colc[3][4];
  #pragma unroll
  for (int ky = 0; ky < 3; ++ky) {
    colc[ky][0] = a[ky * 3 + 0];
    colc[ky][1] = a[ky * 3 + 1] + a[ky * 3 + 2];
    colc[ky][2] = a[ky * 3 + 0] + a[ky * 3 + 1];
    colc[ky][3] = a[ky * 3 + 2];
  }
  float* o = weff + (long)i * 16;
  #pragma unroll
  for (int px = 0; px < 2; ++px) {
    #pragma unroll
    for (int ix = 0; ix < 2; ++ix) {
      int j = px * 2 + ix;
      o[(0 * 2 + px) * 4 + 0 * 2 + ix] = colc[0][j];
      o[(0 * 2 + px) * 4 + 1 * 2 + ix] = colc[1][j] + colc[2][j];
      o[(1 * 2 + px) * 4 + 0 * 2 + ix] = colc[0][j] + colc[1][j];
      o[(1 * 2 + px) * 4 + 1 * 2 + ix] = colc[2][j];
    }
  }
}

// ---------------- stride-2 conv3x3 (d1,d2,d3), 2 px/thread ----------------
template<int CIN, int COB, int NOCB, int CK, int OH, int OW>
__global__ __launch_bounds__(256, 4) void convs2_k(
    const float* __restrict__ in, long in_nstride,
    const float* __restrict__ wgt, const float* __restrict__ bias,
    float* __restrict__ out, long out_nstride, int out_coff) {
  constexpr int TX = 32, TY = 16;
  constexpr int IW = 2 * OW, IH = 2 * OH;
  constexpr int LW = 2 * TX + 2;  // 66
  constexpr int LH = 2 * TY + 1;  // 33
  constexpr long OHW = (long)OH * OW;
  __shared__ float lds[CK][LH][LW];
  int tid = threadIdx.x;
  int ox = tid & 15, oy = tid >> 4;
  int z = blockIdx.z;
  int n = z / NOCB;
  int oc_base = (z % NOCB) * COB;
  int X0 = blockIdx.x * TX, Y0 = blockIdx.y * TY;
  int ix0 = 2 * X0, iy0 = 2 * Y0;

  float acc[COB][2];
  #pragma unroll
  for (int o = 0; o < COB; ++o) { acc[o][0] = 0.f; acc[o][1] = 0.f; }

  for (int c0 = 0; c0 < CIN; c0 += CK) {
    #pragma unroll
    for (int c = 0; c < CK; ++c) {
      const float* src = in + (long)n * in_nstride + (long)(c0 + c) * (IH * (long)IW);
      for (int i = tid; i < LH * LW; i += 256) {
        int r = i / LW, col = i - r * LW;
        int gy = iy0 + r, gx = ix0 + col;
        float v = 0.f;
        if (gy < IH && gx < IW) v = src[(long)gy * IW + gx];
        lds[c][r][col] = v;
      }
    }
    __syncthreads();
    #pragma unroll
    for (int c = 0; c < CK; ++c) {
      float v[2][9];
      #pragma unroll
      for (int i = 0; i < 2; ++i)
        #pragma unroll
        for (int ky = 0; ky < 3; ++ky)
          #pragma unroll
          for (int kx = 0; kx < 3; ++kx)
            v[i][ky * 3 + kx] = lds[c][2 * oy + ky][2 * (ox + 16 * i) + kx];
      #pragma unroll
      for (int oc = 0; oc < COB; ++oc) {
        const float* w9 = wgt + ((long)(oc_base + oc) * CIN + (c0 + c)) * 9;
        #pragma unroll
        for (int t = 0; t < 9; ++t) {
          acc[oc][0] = fmaf(w9[t], v[0][t], acc[oc][0]);
          acc[oc][1] = fmaf(w9[t], v[1][t], acc[oc][1]);
        }
      }
    }
    __syncthreads();
  }

  int oyg = Y0 + oy;
  #pragma unroll
  for (int i = 0; i < 2; ++i) {
    int oxg = X0 + ox + 16 * i;
    long pix = (long)oyg * OW + oxg;
    #pragma unroll
    for (int oc = 0; oc < COB; ++oc) {
      float x = acc[oc][i] + bias[oc_base + oc];
      x = x >= 0.f ? x : 0.2f * x;
      out[(long)n * out_nstride + (long)(out_coff + oc_base + oc) * OHW + pix] = x;
    }
  }
}

// ---------------- up2-folded stride-1 conv (u3,u2): 1 quad/thread ----------
template<int CIN, int COB, int NOCB, int CK, int SH>
__global__ __launch_bounds__(256, 4) void convup_k(
    const float* __restrict__ in, long in_nstride,
    const float* __restrict__ weff, const float* __restrict__ bias,
    float* __restrict__ out, long out_nstride, int out_coff) {
  constexpr int SW = SH;
  constexpr int OW = 2 * SW;
  constexpr long OHW = (long)OW * OW;
  constexpr int LH = 18, LW = 40;
  __shared__ float lds[CK][LH][LW];
  int tid = threadIdx.x;
  int qx = tid & 15, qy = tid >> 4;
  int z = blockIdx.z;
  int n = z / NOCB;
  int oc_base = (z % NOCB) * COB;
  int QX0 = blockIdx.x * 16, QY0 = blockIdx.y * 16;

  float acc[COB][4];
  #pragma unroll
  for (int o = 0; o < COB; ++o)
    #pragma unroll
    for (int p = 0; p < 4; ++p) acc[o][p] = 0.f;

  for (int c0 = 0; c0 < CIN; c0 += CK) {
    for (int i = tid; i < CK * LH * 18; i += 256) {
      int c = i / (LH * 18);
      int rem = i - c * (LH * 18);
      int r = rem / 18, col = rem - r * 18;
      int gy = QY0 - 1 + r, gx = QX0 - 1 + col;
      float v = 0.f;
      if ((unsigned)gy < (unsigned)SH && (unsigned)gx < (unsigned)SW)
        v = in[(long)n * in_nstride + (long)(c0 + c) * (SH * (long)SW) + (long)gy * SW + gx];
      lds[c][r][col] = v;
    }
    __syncthreads();
    #pragma unroll
    for (int c = 0; c < CK; ++c) {
      float s[3][3];
      #pragma unroll
      for (int j = 0; j < 3; ++j)
        #pragma unroll
        for (int i = 0; i < 3; ++i)
          s[j][i] = lds[c][qy + j][qx + i];
      #pragma unroll
      for (int oc = 0; oc < COB; ++oc) {
        const float* W = weff + ((long)(oc_base + oc) * CIN + (c0 + c)) * 16;
        acc[oc][0] = fmaf(W[0], s[0][0], fmaf(W[1], s[0][1], fmaf(W[2], s[1][0], fmaf(W[3], s[1][1], acc[oc][0]))));
        acc[oc][1] = fmaf(W[4], s[0][1], fmaf(W[5], s[0][2], fmaf(W[6], s[1][1], fmaf(W[7], s[1][2], acc[oc][1]))));
        acc[oc][2] = fmaf(W[8], s[1][0], fmaf(W[9], s[1][1], fmaf(W[10], s[2][0], fmaf(W[11], s[2][1], acc[oc][2]))));
        acc[oc][3] = fmaf(W[12], s[1][1], fmaf(W[13], s[1][2], fmaf(W[14], s[2][1], fmaf(W[15], s[2][2], acc[oc][3]))));
      }
    }
    __syncthreads();
  }

  #pragma unroll
  for (int p = 0; p < 4; ++p) {
    int py = p >> 1, px = p & 1;
    int oyg = 2 * (QY0 + qy) + py;
    int oxg = 2 * (QX0 + qx) + px;
    long pix = (long)oyg * OW + oxg;
    #pragma unroll
    for (int oc = 0; oc < COB; ++oc) {
      float x = acc[oc][p] + bias[oc_base + oc];
      x = x >= 0.f ? x : 0.2f * x;
      out[(long)n * out_nstride + (long)(out_coff + oc_base + oc) * OHW + pix] = x;
    }
  }
}

// ---------------- u1: up2-folded conv 64->27 fused with final ----------------
__global__ __launch_bounds__(256, 4) void convup_fuse_k(
    const float* __restrict__ in,         // d1cat (2,64,256,256)
    const float* __restrict__ weff,       // 27*64*16
    const float* __restrict__ bias,       // 27
    const float* __restrict__ m_in,       // (2,9,512,512)
    const float* __restrict__ alb_in,     // (2,3,512,512)
    float* __restrict__ fin_out) {
  constexpr int CK = 8, SH = 256, SW = 256;
  constexpr int LH = 10, LW = 40;
  __shared__ float lds[CK][LH][LW];
  int tid = threadIdx.x;
  int qx = tid & 15;
  int waveu = __builtin_amdgcn_readfirstlane(tid >> 6);   // wave-uniform SGPR
  int py = waveu & 1;
  int qy = ((waveu >> 1) << 2) + ((tid >> 4) & 3);
  int n = blockIdx.z;
  int QX0 = blockIdx.x * 16, QY0 = blockIdx.y * 8;

  float acc[27][2];
  #pragma unroll
  for (int o = 0; o < 27; ++o) { acc[o][0] = 0.f; acc[o][1] = 0.f; }

  for (int c0 = 0; c0 < 64; c0 += CK) {
    for (int i = tid; i < CK * LH * 18; i += 256) {
      int c = i / (LH * 18);
      int rem = i - c * (LH * 18);
      int r = rem / 18, col = rem - r * 18;
      int gy = QY0 - 1 + r, gx = QX0 - 1 + col;
      float v = 0.f;
      if ((unsigned)gy < (unsigned)SH && (unsigned)gx < (unsigned)SW)
        v = in[(long)n * (64L * 65536) + (long)(c0 + c) * 65536 + (long)gy * SW + gx];
      lds[c][r][col] = v;
    }
    __syncthreads();
    #pragma unroll
    for (int c = 0; c < CK; ++c) {
      float s[2][3];
      #pragma unroll
      for (int j = 0; j < 2; ++j)
        #pragma unroll
        for (int i = 0; i < 3; ++i)
          s[j][i] = lds[c][qy + py + j][qx + i];
      #pragma unroll
      for (int oc = 0; oc < 27; ++oc) {
        const float* W = weff + ((long)oc * 64 + (c0 + c)) * 16 + py * 8;
        acc[oc][0] = fmaf(W[0], s[0][0], fmaf(W[1], s[0][1], fmaf(W[2], s[1][0], fmaf(W[3], s[1][1], acc[oc][0]))));
        acc[oc][1] = fmaf(W[4], s[0][1], fmaf(W[5], s[0][2], fmaf(W[6], s[1][1], fmaf(W[7], s[1][2], acc[oc][1]))));
      }
    }
    __syncthreads();
  }

  int oyg = 2 * (QY0 + qy) + py;
  #pragma unroll
  for (int px = 0; px < 2; ++px) {
    int oxg = 2 * (QX0 + qx) + px;
    long pix = (long)oyg * 512 + oxg;
    float s0 = 0.f, s1 = 0.f, s2 = 0.f;
    #pragma unroll
    for (int k = 0; k < 9; ++k) {
      float mk = m_in[((long)n * 9 + k) * HW + pix];
      s0 = fmaf(mk, acc[3 * k + 0][px] + bias[3 * k + 0], s0);
      s1 = fmaf(mk, acc[3 * k + 1][px] + bias[3 * k + 1], s1);
      s2 = fmaf(mk, acc[3 * k + 2][px] + bias[3 * k + 2], s2);
    }
    fin_out[((long)n * 3 + 0) * HW + pix] = alb_in[((long)n * 3 + 0) * HW + pix] * s0;
    fin_out[((long)n * 3 + 1) * HW + pix] = alb_in[((long)n * 3 + 1) * HW + pix] * s1;
    fin_out[((long)n * 3 + 2) * HW + pix] = alb_in[((long)n * 3 + 2) * HW + pix] * s2;
  }
}

// ---------------- launch ----------------
extern "C" void kernel_launch(void* const* d_in, const int* in_sizes, int n_in,
                              void* d_out, int out_size, void* d_ws, size_t ws_size,
                              hipStream_t stream) {
  const float* wi   = (const float*)d_in[0];
  const float* env  = (const float*)d_in[1];
  const float* uv   = (const float*)d_in[2];
  const float* ext  = (const float*)d_in[3];
  const float* atex = (const float*)d_in[4];
  const float* t1   = (const float*)d_in[5];
  const float* t2   = (const float*)d_in[6];
  const float* t3   = (const float*)d_in[7];
  const float* t4   = (const float*)d_in[8];
  const float* w_d1 = (const float*)d_in[9];
  const float* b_d1 = (const float*)d_in[10];
  const float* w_d2 = (const float*)d_in[11];
  const float* b_d2 = (const float*)d_in[12];
  const float* w_d3 = (const float*)d_in[13];
  const float* b_d3 = (const float*)d_in[14];
  const float* w_u3 = (const float*)d_in[15];
  const float* b_u3 = (const float*)d_in[16];
  const float* w_u2 = (const float*)d_in[17];
  const float* b_u2 = (const float*)d_in[18];
  const float* w_u1 = (const float*)d_in[19];
  const float* b_u1 = (const float*)d_in[20];
  float* out = (float*)d_out;
  float* ws  = (float*)d_ws;

  float* m_buf = ws + OFF_M;
  float* nt_buf = ws + OFF_NT;
  float* d2cat = ws + OFF_D2C;
  float* d3buf = ws + OFF_D3;
  float* d1cat = ws + OFF_D1C;
  float* we3 = ws + OFF_WE3;
  float* we2 = ws + OFF_WE2;
  float* we1 = ws + OFF_WE1;

  // interleaved textures (alias d1cat region; dead before d1 writes it)
  transpose16_k<HW><<<1024, 256, 0, stream>>>(t1, ws + OFF_T1);
  transpose16_k<65536><<<256, 256, 0, stream>>>(t2, ws + OFF_T2);
  transpose16_k<16384><<<64, 256, 0, stream>>>(t3, ws + OFF_T3);
  transpose16_k<4096><<<16, 256, 0, stream>>>(t4, ws + OFF_T4);
  transpose3_k<<<1024, 256, 0, stream>>>(atex, ws + OFF_TA);

  // stage A1: uv gather -> nt, albedo
  sample_tex_k<<<2048, 256, 0, stream>>>(uv, ext, ws + OFF_TA, ws + OFF_T1,
                                         ws + OFF_T2, ws + OFF_T3, ws + OFF_T4,
                                         nt_buf, out + OUT_ALB);
  // stage A2: wi/env streaming -> m, fwd
  sh_env_k<<<2048, 256, 0, stream>>>(wi, env, out + OUT_ALB, m_buf, out + OUT_FWD);

  copy4_k<<<768, 256, 0, stream>>>((const float4*)atex, (float4*)out, 196608);

  // d1: nt(16,512^2) -> d1cat[32:64] (32,256^2)  [overwrites texture region]
  convs2_k<16, 16, 2, 4, 256, 256><<<dim3(8, 16, 4), 256, 0, stream>>>(
      nt_buf, 16L * HW, w_d1, b_d1, d1cat, 64L * 65536, 32);

  // expand up2-folded weights (aliases dead nt tail -> after d1)
  expand_w_k<<<32, 256, 0, stream>>>(w_u3, we3, 64 * 128);
  expand_w_k<<<16, 256, 0, stream>>>(w_u2, we2, 32 * 128);
  expand_w_k<<<7, 256, 0, stream>>>(w_u1, we1, 27 * 64);

  // d2: d1cat[32:64] -> d2cat[64:128] (64,128^2)
  convs2_k<32, 8, 8, 4, 128, 128><<<dim3(4, 8, 16), 256, 0, stream>>>(
      d1cat + 32L * 65536, 64L * 65536, w_d2, b_d2, d2cat, 128L * 16384, 64);

  // d3: d2cat[64:128] -> d3 (128,64^2)
  convs2_k<64, 4, 32, 4, 64, 64><<<dim3(2, 4, 64), 256, 0, stream>>>(
      d2cat + 64L * 16384, 128L * 16384, w_d3, b_d3, d3buf, 128L * 4096, 0);

  // u3: up2(d3) conv -> d2cat[0:64] (64,128^2)
  convup_k<128, 4, 16, 8, 64><<<dim3(4, 4, 32), 256, 0, stream>>>(
      d3buf, 128L * 4096, we3, b_u3, d2cat, 128L * 16384, 0);

  // u2: up2(d2cat) conv -> d1cat[0:32] (32,256^2)
  convup_k<128, 8, 4, 8, 128><<<dim3(8, 8, 8), 256, 0, stream>>>(
      d2cat, 128L * 16384, we2, b_u2, d1cat, 64L * 65536, 0);

  // u1: up2(d1cat) conv 64->27 fused with final-dot
  convup_fuse_k<<<dim3(16, 32, 2), 256, 0, stream>>>(
      d1cat, we1, b_u1, m_buf, out + OUT_ALB, out + OUT_FINAL);
}

// Round 5
// 955.657 us; speedup vs baseline: 3.3532x; 1.4388x over previous
//
#include <hip/hip_runtime.h>

// ---------------- constants / layout ----------------
constexpr int HW = 512 * 512; // 262144

// d_out layout (floats)
constexpr long OUT_FINAL = 786432;
constexpr long OUT_FWD   = 2359296;
constexpr long OUT_ALB   = 3932160;

// workspace layout (floats) — all activations NHWC
constexpr long OFF_M    = 0;         // m NHWC 8ch: (2,512,512,8)  = 4,194,304
constexpr long OFF_ALBN = 4194304;   // alb NHWC 4ch: (2,512,512,4)= 2,097,152
constexpr long OFF_NT   = 6291456;   // nt NHWC: (2,512,512,16)    = 8,388,608 (dies after d1)
constexpr long OFF_D2C  = 6291456;   // d2cat NHWC: (2,128,128,128)= 4,194,304 (alias nt)
constexpr long OFF_D3   = 10485760;  // d3 NHWC: (2,64,64,128)     = 1,048,576 (alias nt tail)
constexpr long OFF_D1C  = 14680064;  // d1cat NHWC: (2,256,256,64) = 8,388,608
// interleaved textures alias d1cat (dead before d1 writes it)
constexpr long OFF_TA   = 14680064;  // (512,512,4)
constexpr long OFF_T1   = 15728640;  // (512,512,16)
constexpr long OFF_T2   = 19922944;  // (256,256,16)
constexpr long OFF_T3   = 20971520;  // (128,128,16)
constexpr long OFF_T4   = 21233664;  // (64,64,16)
// repacked weights
constexpr long OFF_WD1  = 23068672;  // 32*16*9*? -> [icg][32][9][4]  = 4608
constexpr long OFF_WD2  = 23073280;  // [8][64][9][4]   = 18432
constexpr long OFF_WD3  = 23091712;  // [16][128][9][4] = 73728
constexpr long OFF_WU3  = 23165440;  // [32][64][16][4] = 131072
constexpr long OFF_WU2  = 23296512;  // [32][32][16][4] = 65536
constexpr long OFF_WU1  = 23362048;  // [16][27][16][4] = 27648
// end 23,389,696 floats ~= 93.6 MB

// ---------------- bilinear helpers ----------------
__device__ __forceinline__ void bl_setup(float u, float v, int T,
                                         int& x0, int& y0, float& wx, float& wy) {
  float px = u * (float)(T - 1);
  float py = v * (float)(T - 1);
  int xi = (int)floorf(px);
  int yi = (int)floorf(py);
  xi = xi < 0 ? 0 : (xi > T - 2 ? T - 2 : xi);
  yi = yi < 0 ? 0 : (yi > T - 2 ? T - 2 : yi);
  wx = px - (float)xi;
  wy = py - (float)yi;
  x0 = xi; y0 = yi;
}

template<int T>
__device__ __forceinline__ void sample16i(const float* __restrict__ tex,
                                          float u, float v, float* nt) {
  int x0, y0; float wx, wy;
  bl_setup(u, v, T, x0, y0, wx, wy);
  float w00 = (1.f - wx) * (1.f - wy), w01 = wx * (1.f - wy);
  float w10 = (1.f - wx) * wy,         w11 = wx * wy;
  const float4* b = (const float4*)tex;
  int i00 = (y0 * T + x0) * 4;
  #pragma unroll
  for (int g = 0; g < 4; ++g) {
    float4 v00 = b[i00 + g];
    float4 v01 = b[i00 + 4 + g];
    float4 v10 = b[i00 + T * 4 + g];
    float4 v11 = b[i00 + T * 4 + 4 + g];
    nt[4 * g + 0] += v00.x * w00 + v01.x * w01 + v10.x * w10 + v11.x * w11;
    nt[4 * g + 1] += v00.y * w00 + v01.y * w01 + v10.y * w10 + v11.y * w11;
    nt[4 * g + 2] += v00.z * w00 + v01.z * w01 + v10.z * w10 + v11.z * w11;
    nt[4 * g + 3] += v00.w * w00 + v01.w * w01 + v10.w * w10 + v11.w * w11;
  }
}

// ---------------- texture transposes: (C,H,W) -> (H,W,C) ----------------
template<int NPIX>
__global__ __launch_bounds__(256) void transpose16_k(const float* __restrict__ src,
                                                     float* __restrict__ dst) {
  int p = blockIdx.x * 256 + threadIdx.x;
  if (p >= NPIX) return;
  float v[16];
  #pragma unroll
  for (int c = 0; c < 16; ++c) v[c] = src[(long)c * NPIX + p];
  float4* d = (float4*)(dst + (long)p * 16);
  d[0] = make_float4(v[0], v[1], v[2], v[3]);
  d[1] = make_float4(v[4], v[5], v[6], v[7]);
  d[2] = make_float4(v[8], v[9], v[10], v[11]);
  d[3] = make_float4(v[12], v[13], v[14], v[15]);
}

__global__ __launch_bounds__(256) void transpose3_k(const float* __restrict__ src,
                                                    float* __restrict__ dst) {
  int p = blockIdx.x * 256 + threadIdx.x;
  if (p >= HW) return;
  ((float4*)dst)[p] = make_float4(src[p], src[HW + p], src[2 * HW + p], 0.f);
}

// ---------------- weight repacks ----------------
// stride2: w (OC,CIN,3,3) -> wr[icg][OC][9][4]
__global__ __launch_bounds__(256) void repack_s2_k(const float* __restrict__ w,
                                                   float* __restrict__ wr,
                                                   int OC, int CIN) {
  int i = blockIdx.x * 256 + threadIdx.x;
  if (i >= OC * CIN) return;
  int oc = i / CIN, ic = i - oc * CIN;
  int icg = ic >> 2, j = ic & 3;
  #pragma unroll
  for (int t = 0; t < 9; ++t)
    wr[(((long)icg * OC + oc) * 9 + t) * 4 + j] = w[(long)i * 9 + t];
}

// up2-folded: w (OC,CIN,3,3) -> W2 16 taps -> wr[icg][OC][16][4]
__global__ __launch_bounds__(256) void repack_up_k(const float* __restrict__ w,
                                                   float* __restrict__ wr,
                                                   int OC, int CIN) {
  int i = blockIdx.x * 256 + threadIdx.x;
  if (i >= OC * CIN) return;
  int oc = i / CIN, ic = i - oc * CIN;
  float a[9];
  #pragma unroll
  for (int t = 0; t < 9; ++t) a[t] = w[(long)i * 9 + t];
  float colc[3][4];
  #pragma unroll
  for (int ky = 0; ky < 3; ++ky) {
    colc[ky][0] = a[ky * 3 + 0];
    colc[ky][1] = a[ky * 3 + 1] + a[ky * 3 + 2];
    colc[ky][2] = a[ky * 3 + 0] + a[ky * 3 + 1];
    colc[ky][3] = a[ky * 3 + 2];
  }
  int icg = ic >> 2, j = ic & 3;
  float* o = wr + (((long)icg * OC + oc) * 16) * 4 + j;
  #pragma unroll
  for (int px = 0; px < 2; ++px) {
    #pragma unroll
    for (int ix = 0; ix < 2; ++ix) {
      int q = px * 2 + ix;
      o[((0 * 2 + px) * 4 + 0 * 2 + ix) * 4] = colc[0][q];
      o[((0 * 2 + px) * 4 + 1 * 2 + ix) * 4] = colc[1][q] + colc[2][q];
      o[((1 * 2 + px) * 4 + 0 * 2 + ix) * 4] = colc[0][q] + colc[1][q];
      o[((1 * 2 + px) * 4 + 1 * 2 + ix) * 4] = colc[2][q];
    }
  }
}

// ---------------- stage A1: uv-gather -> nt NHWC, albedo ----------------
__global__ __launch_bounds__(256, 4) void sample_tex_k(
    const float* __restrict__ uv, const float* __restrict__ ext,
    const float* __restrict__ TA, const float* __restrict__ T1,
    const float* __restrict__ T2, const float* __restrict__ T3,
    const float* __restrict__ T4,
    float4* __restrict__ nt_out, float* __restrict__ alb_out,
    float4* __restrict__ albn_out) {
  int idx = blockIdx.x * 256 + threadIdx.x;
  int n = idx >> 18;
  int p = idx & (HW - 1);
  float2 uvv = reinterpret_cast<const float2*>(uv)[idx];
  float u = uvv.x, v = uvv.y;

  int x0, y0; float wx, wy;
  bl_setup(u, v, 512, x0, y0, wx, wy);
  float w00 = (1.f - wx) * (1.f - wy), w01 = wx * (1.f - wy);
  float w10 = (1.f - wx) * wy,         w11 = wx * wy;
  const float4* A = (const float4*)TA;
  float4 a00 = A[y0 * 512 + x0], a01 = A[y0 * 512 + x0 + 1];
  float4 a10 = A[(y0 + 1) * 512 + x0], a11 = A[(y0 + 1) * 512 + x0 + 1];
  float alb0 = a00.x * w00 + a01.x * w01 + a10.x * w10 + a11.x * w11;
  float alb1 = a00.y * w00 + a01.y * w01 + a10.y * w10 + a11.y * w11;
  float alb2 = a00.z * w00 + a01.z * w01 + a10.z * w10 + a11.z * w11;

  float nt[16];
  #pragma unroll
  for (int c = 0; c < 16; ++c) nt[c] = 0.f;
  sample16i<512>(T1, u, v, nt);
  sample16i<256>(T2, u, v, nt);
  sample16i<128>(T3, u, v, nt);
  sample16i<64>(T4, u, v, nt);

  const float C0f = 0.28209479177387814f, C1f = 0.4886025119029199f;
  const float C2f = 1.0925484305920792f, C20f = 0.31539156525252005f;
  const float SQ = 0.70710678118654752f;
  float ex = ext[n * 3 + 0], ey = ext[n * 3 + 1], ez = ext[n * 3 + 2];
  float basis[9];
  basis[0] = C0f;
  basis[1] = ey * C1f * SQ;
  basis[2] = ez * C1f;
  basis[3] = -ex * C1f * SQ;
  basis[4] = ex * ey * C2f * 0.5f * SQ;
  basis[5] = ey * ez * C2f * SQ;
  basis[6] = (3.f * ez * ez - 1.f) * C20f;
  basis[7] = -ez * ex * C2f * SQ;
  basis[8] = (ex * ex - ez * ez) * C2f * 0.5f * SQ;
  #pragma unroll
  for (int j = 0; j < 9; ++j) nt[3 + j] *= basis[j];

  float4* nb = nt_out + (long)idx * 4;
  nb[0] = make_float4(nt[0], nt[1], nt[2], nt[3]);
  nb[1] = make_float4(nt[4], nt[5], nt[6], nt[7]);
  nb[2] = make_float4(nt[8], nt[9], nt[10], nt[11]);
  nb[3] = make_float4(nt[12], nt[13], nt[14], nt[15]);

  albn_out[idx] = make_float4(alb0, alb1, alb2, 0.f);
  alb_out[((long)n * 3 + 0) * HW + p] = alb0;
  alb_out[((long)n * 3 + 1) * HW + p] = alb1;
  alb_out[((long)n * 3 + 2) * HW + p] = alb2;
}

// ---------------- stage A2: SH/env streaming reduce -> m NHWC(8), fwd ------
__global__ __launch_bounds__(256, 4) void sh_env_k(
    const float* __restrict__ wi, const float* __restrict__ env,
    const float4* __restrict__ albn,
    float4* __restrict__ m_out, float* __restrict__ fwd_out) {
  int idx = blockIdx.x * 256 + threadIdx.x;
  int n = idx >> 18;
  int p = idx & (HW - 1);

  const float C1f = 0.4886025119029199f;
  const float C2f = 1.0925484305920792f, C20f = 0.31539156525252005f;
  const float C22f = 0.5462742152960396f;

  float ms[8];
  #pragma unroll
  for (int j = 0; j < 8; ++j) ms[j] = 0.f;
  float es[3] = {0.f, 0.f, 0.f};

  const float* wb = wi + ((long)n * 20) * HW + p;
  const float* eb = env + ((long)n * 30) * HW + p;
  #pragma unroll
  for (int ss = 0; ss < 10; ++ss) {
    float th = __builtin_nontemporal_load(&wb[(long)ss * HW]);
    float ph = __builtin_nontemporal_load(&wb[(long)(10 + ss) * HW]);
    float st, ct, sp, cp;
    sincosf(th, &st, &ct);
    sincosf(ph, &sp, &cp);
    float x = st * cp, y = st * sp, z = ct;
    ms[0] += y; ms[1] += z; ms[2] += x;
    ms[3] += x * y; ms[4] += y * z;
    ms[5] += 3.f * z * z - 1.f;
    ms[6] += x * z; ms[7] += x * x - y * y;
    es[0] += __builtin_nontemporal_load(&eb[(long)ss * HW]);
    es[1] += __builtin_nontemporal_load(&eb[(long)(10 + ss) * HW]);
    es[2] += __builtin_nontemporal_load(&eb[(long)(20 + ss) * HW]);
  }

  float m1 = C1f * ms[0] * 0.1f, m2 = C1f * ms[1] * 0.1f, m3 = C1f * ms[2] * 0.1f;
  float m4 = C2f * ms[3] * 0.1f, m5 = C2f * ms[4] * 0.1f, m6 = C20f * ms[5] * 0.1f;
  float m7 = C2f * ms[6] * 0.1f, m8 = C22f * ms[7] * 0.1f;

  m_out[(long)idx * 2 + 0] = make_float4(m1, m2, m3, m4);
  m_out[(long)idx * 2 + 1] = make_float4(m5, m6, m7, m8);

  float4 al = albn[idx];
  __builtin_nontemporal_store(al.x * es[0] * 0.1f, &fwd_out[((long)n * 3 + 0) * HW + p]);
  __builtin_nontemporal_store(al.y * es[1] * 0.1f, &fwd_out[((long)n * 3 + 1) * HW + p]);
  __builtin_nontemporal_store(al.z * es[2] * 0.1f, &fwd_out[((long)n * 3 + 2) * HW + p]);
}

// ---------------- albedo_tex copy ----------------
__global__ __launch_bounds__(256) void copy4_k(const float4* __restrict__ s,
                                               float4* __restrict__ d, int n) {
  int i = blockIdx.x * 256 + threadIdx.x;
  if (i < n) d[i] = s[i];
}

// ---------------- NHWC stride-2 conv3x3 (d1,d2,d3) ----------------
// thread = 1 out px; tile 32x8; LDS holds one ic4-group of the src tile.
template<int CIN, int RECI, int COFFI, int COB, int RECO, int COFFO, int NOCB, int OH>
__global__ __launch_bounds__(256, 4) void convs2_nhwc_k(
    const float4* __restrict__ in, const float* __restrict__ wr,
    const float* __restrict__ bias, float4* __restrict__ outp) {
  constexpr int OW = OH;
  constexpr int IH = 2 * OH, IW = 2 * OW;
  constexpr int OC = COB * NOCB;
  constexpr int TX = 32, TY = 8;
  constexpr int LH = 2 * TY + 1, LW = 2 * TX + 2; // 17 x 66
  __shared__ float4 lds[LH][LW + 1];
  int tid = threadIdx.x;
  int ox = tid & 31, oy = tid >> 5;
  int z = blockIdx.z;
  int n = z / NOCB;
  int oc_base = (z % NOCB) * COB;
  int X0 = blockIdx.x * TX, Y0 = blockIdx.y * TY;
  int ix0 = 2 * X0, iy0 = 2 * Y0;
  const float4* inb = in + (long)n * ((long)IH * IW * (RECI / 4));

  float acc[COB];
  #pragma unroll
  for (int o = 0; o < COB; ++o) acc[o] = 0.f;

  for (int icg = 0; icg < CIN / 4; ++icg) {
    __syncthreads();
    for (int i = tid; i < LH * LW; i += 256) {
      int r = i / LW, col = i - r * LW;
      int gy = iy0 + r, gx = ix0 + col;
      float4 v = make_float4(0.f, 0.f, 0.f, 0.f);
      if (gy < IH && gx < IW)
        v = inb[((long)gy * IW + gx) * (RECI / 4) + (COFFI / 4) + icg];
      lds[r][col] = v;
    }
    __syncthreads();
    float4 s[9];
    #pragma unroll
    for (int ky = 0; ky < 3; ++ky)
      #pragma unroll
      for (int kx = 0; kx < 3; ++kx)
        s[ky * 3 + kx] = lds[2 * oy + ky][2 * ox + kx];
    const float* wb = wr + ((long)icg * OC + oc_base) * 36;
    #pragma unroll
    for (int oc = 0; oc < COB; ++oc) {
      const float* wo = wb + oc * 36;
      float a = acc[oc];
      #pragma unroll
      for (int t = 0; t < 9; ++t) {
        a = fmaf(wo[t * 4 + 0], s[t].x, a);
        a = fmaf(wo[t * 4 + 1], s[t].y, a);
        a = fmaf(wo[t * 4 + 2], s[t].z, a);
        a = fmaf(wo[t * 4 + 3], s[t].w, a);
      }
      acc[oc] = a;
    }
  }

  long opix = (long)n * OH * OW + (long)(Y0 + oy) * OW + (X0 + ox);
  float4* ob = outp + opix * (RECO / 4) + (COFFO / 4) + (oc_base / 4);
  #pragma unroll
  for (int g = 0; g < COB / 4; ++g) {
    float x0v = acc[4 * g + 0] + bias[oc_base + 4 * g + 0];
    float x1v = acc[4 * g + 1] + bias[oc_base + 4 * g + 1];
    float x2v = acc[4 * g + 2] + bias[oc_base + 4 * g + 2];
    float x3v = acc[4 * g + 3] + bias[oc_base + 4 * g + 3];
    ob[g] = make_float4(x0v >= 0.f ? x0v : 0.2f * x0v,
                        x1v >= 0.f ? x1v : 0.2f * x1v,
                        x2v >= 0.f ? x2v : 0.2f * x2v,
                        x3v >= 0.f ? x3v : 0.2f * x3v);
  }
}

// ---------------- NHWC up2-folded conv (u3,u2): thread = 1 quad ----------
template<int CIN, int RECI, int COFFI, int COB, int RECO, int COFFO, int NOCB, int SH>
__global__ __launch_bounds__(256, 4) void convup_nhwc_k(
    const float4* __restrict__ in, const float* __restrict__ wr,
    const float* __restrict__ bias, float4* __restrict__ outp) {
  constexpr int SW = SH, OW = 2 * SW;
  constexpr int OC = COB * NOCB;
  __shared__ float4 lds[18][19][2];
  int tid = threadIdx.x;
  int qx = tid & 15, qy = tid >> 4;
  int z = blockIdx.z;
  int n = z / NOCB;
  int oc_base = (z % NOCB) * COB;
  int QX0 = blockIdx.x * 16, QY0 = blockIdx.y * 16;
  const float4* inb = in + (long)n * ((long)SH * SW * (RECI / 4));

  float acc[COB][4];
  #pragma unroll
  for (int o = 0; o < COB; ++o)
    #pragma unroll
    for (int p = 0; p < 4; ++p) acc[o][p] = 0.f;

  for (int cc = 0; cc < CIN / 8; ++cc) {
    __syncthreads();
    for (int i = tid; i < 18 * 18 * 2; i += 256) {
      int sl = i & 1;
      int r2 = i >> 1;
      int r = r2 / 18, col = r2 - r * 18;
      int gy = QY0 - 1 + r, gx = QX0 - 1 + col;
      float4 v = make_float4(0.f, 0.f, 0.f, 0.f);
      if ((unsigned)gy < (unsigned)SH && (unsigned)gx < (unsigned)SW)
        v = inb[((long)gy * SW + gx) * (RECI / 4) + (COFFI / 4) + cc * 2 + sl];
      lds[r][col][sl] = v;
    }
    __syncthreads();
    #pragma unroll
    for (int sl = 0; sl < 2; ++sl) {
      float4 s[3][3];
      #pragma unroll
      for (int j = 0; j < 3; ++j)
        #pragma unroll
        for (int i = 0; i < 3; ++i)
          s[j][i] = lds[qy + j][qx + i][sl];
      int icg = cc * 2 + sl;
      const float* wb = wr + ((long)icg * OC + oc_base) * 64;
      #pragma unroll
      for (int oc = 0; oc < COB; ++oc) {
        const float* wo = wb + oc * 64;
        #pragma unroll
        for (int py = 0; py < 2; ++py)
          #pragma unroll
          for (int px = 0; px < 2; ++px) {
            float a = acc[oc][py * 2 + px];
            #pragma unroll
            for (int iy = 0; iy < 2; ++iy)
              #pragma unroll
              for (int ix = 0; ix < 2; ++ix) {
                const float* w4 = wo + ((py * 2 + px) * 4 + iy * 2 + ix) * 4;
                float4 sv = s[py + iy][px + ix];
                a = fmaf(w4[0], sv.x, a);
                a = fmaf(w4[1], sv.y, a);
                a = fmaf(w4[2], sv.z, a);
                a = fmaf(w4[3], sv.w, a);
              }
            acc[oc][py * 2 + px] = a;
          }
      }
    }
  }

  long pixn = (long)n * OW * OW;
  #pragma unroll
  for (int py = 0; py < 2; ++py)
    #pragma unroll
    for (int px = 0; px < 2; ++px) {
      int oyg = 2 * (QY0 + qy) + py;
      int oxg = 2 * (QX0 + qx) + px;
      float4* ob = outp + (pixn + (long)oyg * OW + oxg) * (RECO / 4)
                   + (COFFO / 4) + (oc_base / 4);
      #pragma unroll
      for (int g = 0; g < COB / 4; ++g) {
        float x0v = acc[4 * g + 0][py * 2 + px] + bias[oc_base + 4 * g + 0];
        float x1v = acc[4 * g + 1][py * 2 + px] + bias[oc_base + 4 * g + 1];
        float x2v = acc[4 * g + 2][py * 2 + px] + bias[oc_base + 4 * g + 2];
        float x3v = acc[4 * g + 3][py * 2 + px] + bias[oc_base + 4 * g + 3];
        ob[g] = make_float4(x0v >= 0.f ? x0v : 0.2f * x0v,
                            x1v >= 0.f ? x1v : 0.2f * x1v,
                            x2v >= 0.f ? x2v : 0.2f * x2v,
                            x3v >= 0.f ? x3v : 0.2f * x3v);
      }
    }
}

// ---------------- u1: NHWC up2-folded 64->27 fused with final ----------------
// thread = (quad, py): py wave-uniform via readfirstlane.
__global__ __launch_bounds__(256, 4) void convup_fuse_nhwc_k(
    const float4* __restrict__ in,      // d1cat NHWC (2,256,256,64)
    const float* __restrict__ wr,       // [16][27][16][4]
    const float* __restrict__ bias,     // 27
    const float4* __restrict__ mn,      // m NHWC 8ch
    const float4* __restrict__ albn,    // alb NHWC
    float* __restrict__ fin_out) {
  __shared__ float4 lds[10][19][2];
  int tid = threadIdx.x;
  int qx = tid & 15;
  int waveu = __builtin_amdgcn_readfirstlane(tid >> 6);
  int py = waveu & 1;
  int qy = ((waveu >> 1) << 2) + ((tid >> 4) & 3);
  int n = blockIdx.z;
  int QX0 = blockIdx.x * 16, QY0 = blockIdx.y * 8;
  const float4* inb = in + (long)n * (65536L * 16);

  float acc[27][2];
  #pragma unroll
  for (int o = 0; o < 27; ++o) { acc[o][0] = 0.f; acc[o][1] = 0.f; }

  for (int cc = 0; cc < 8; ++cc) {
    __syncthreads();
    for (int i = tid; i < 10 * 18 * 2; i += 256) {
      int sl = i & 1;
      int r2 = i >> 1;
      int r = r2 / 18, col = r2 - r * 18;
      int gy = QY0 - 1 + r, gx = QX0 - 1 + col;
      float4 v = make_float4(0.f, 0.f, 0.f, 0.f);
      if ((unsigned)gy < 256u && (unsigned)gx < 256u)
        v = inb[((long)gy * 256 + gx) * 16 + cc * 2 + sl];
      lds[r][col][sl] = v;
    }
    __syncthreads();
    #pragma unroll
    for (int sl = 0; sl < 2; ++sl) {
      float4 s[2][3];
      #pragma unroll
      for (int j = 0; j < 2; ++j)
        #pragma unroll
        for (int i = 0; i < 3; ++i)
          s[j][i] = lds[qy + py + j][qx + i][sl];
      int icg = cc * 2 + sl;
      const float* wb = wr + (long)icg * 27 * 64 + py * 32;
      #pragma unroll
      for (int oc = 0; oc < 27; ++oc) {
        const float* wo = wb + oc * 64;
        #pragma unroll
        for (int px = 0; px < 2; ++px) {
          float a = acc[oc][px];
          #pragma unroll
          for (int iy = 0; iy < 2; ++iy)
            #pragma unroll
            for (int ix = 0; ix < 2; ++ix) {
              const float* w4 = wo + (px * 4 + iy * 2 + ix) * 4;
              float4 sv = s[iy][px + ix];
              a = fmaf(w4[0], sv.x, a);
              a = fmaf(w4[1], sv.y, a);
              a = fmaf(w4[2], sv.z, a);
              a = fmaf(w4[3], sv.w, a);
            }
          acc[oc][px] = a;
        }
      }
    }
  }

  const float C0f = 0.28209479177387814f;
  int oyg = 2 * (QY0 + qy) + py;
  #pragma unroll
  for (int px = 0; px < 2; ++px) {
    int oxg = 2 * (QX0 + qx) + px;
    long pix = (long)oyg * 512 + oxg;
    long idx = (long)n * HW + pix;
    float4 mA = mn[idx * 2 + 0];
    float4 mB = mn[idx * 2 + 1];
    float mk[9] = {C0f, mA.x, mA.y, mA.z, mA.w, mB.x, mB.y, mB.z, mB.w};
    float s0 = 0.f, s1 = 0.f, s2 = 0.f;
    #pragma unroll
    for (int k = 0; k < 9; ++k) {
      s0 = fmaf(mk[k], acc[3 * k + 0][px] + bias[3 * k + 0], s0);
      s1 = fmaf(mk[k], acc[3 * k + 1][px] + bias[3 * k + 1], s1);
      s2 = fmaf(mk[k], acc[3 * k + 2][px] + bias[3 * k + 2], s2);
    }
    float4 al = albn[idx];
    fin_out[((long)n * 3 + 0) * HW + pix] = al.x * s0;
    fin_out[((long)n * 3 + 1) * HW + pix] = al.y * s1;
    fin_out[((long)n * 3 + 2) * HW + pix] = al.z * s2;
  }
}

// ---------------- launch ----------------
extern "C" void kernel_launch(void* const* d_in, const int* in_sizes, int n_in,
                              void* d_out, int out_size, void* d_ws, size_t ws_size,
                              hipStream_t stream) {
  const float* wi   = (const float*)d_in[0];
  const float* env  = (const float*)d_in[1];
  const float* uv   = (const float*)d_in[2];
  const float* ext  = (const float*)d_in[3];
  const float* atex = (const float*)d_in[4];
  const float* t1   = (const float*)d_in[5];
  const float* t2   = (const float*)d_in[6];
  const float* t3   = (const float*)d_in[7];
  const float* t4   = (const float*)d_in[8];
  const float* w_d1 = (const float*)d_in[9];
  const float* b_d1 = (const float*)d_in[10];
  const float* w_d2 = (const float*)d_in[11];
  const float* b_d2 = (const float*)d_in[12];
  const float* w_d3 = (const float*)d_in[13];
  const float* b_d3 = (const float*)d_in[14];
  const float* w_u3 = (const float*)d_in[15];
  const float* b_u3 = (const float*)d_in[16];
  const float* w_u2 = (const float*)d_in[17];
  const float* b_u2 = (const float*)d_in[18];
  const float* w_u1 = (const float*)d_in[19];
  const float* b_u1 = (const float*)d_in[20];
  float* out = (float*)d_out;
  float* ws  = (float*)d_ws;

  float4* mN   = (float4*)(ws + OFF_M);
  float4* albN = (float4*)(ws + OFF_ALBN);
  float4* ntN  = (float4*)(ws + OFF_NT);
  float4* d2cN = (float4*)(ws + OFF_D2C);
  float4* d3N  = (float4*)(ws + OFF_D3);
  float4* d1cN = (float4*)(ws + OFF_D1C);

  // weight repacks (independent region)
  repack_s2_k<<<2, 256, 0, stream>>>(w_d1, ws + OFF_WD1, 32, 16);
  repack_s2_k<<<8, 256, 0, stream>>>(w_d2, ws + OFF_WD2, 64, 32);
  repack_s2_k<<<32, 256, 0, stream>>>(w_d3, ws + OFF_WD3, 128, 64);
  repack_up_k<<<32, 256, 0, stream>>>(w_u3, ws + OFF_WU3, 64, 128);
  repack_up_k<<<16, 256, 0, stream>>>(w_u2, ws + OFF_WU2, 32, 128);
  repack_up_k<<<7, 256, 0, stream>>>(w_u1, ws + OFF_WU1, 27, 64);

  // texture transposes (alias d1cat region; dead until d1 writes)
  transpose16_k<HW><<<1024, 256, 0, stream>>>(t1, ws + OFF_T1);
  transpose16_k<65536><<<256, 256, 0, stream>>>(t2, ws + OFF_T2);
  transpose16_k<16384><<<64, 256, 0, stream>>>(t3, ws + OFF_T3);
  transpose16_k<4096><<<16, 256, 0, stream>>>(t4, ws + OFF_T4);
  transpose3_k<<<1024, 256, 0, stream>>>(atex, ws + OFF_TA);

  // stage A
  sample_tex_k<<<2048, 256, 0, stream>>>(uv, ext, ws + OFF_TA, ws + OFF_T1,
                                         ws + OFF_T2, ws + OFF_T3, ws + OFF_T4,
                                         ntN, out + OUT_ALB, albN);
  sh_env_k<<<2048, 256, 0, stream>>>(wi, env, albN, mN, out + OUT_FWD);
  copy4_k<<<768, 256, 0, stream>>>((const float4*)atex, (float4*)out, 196608);

  // d1: nt NHWC(16) -> d1cat[32:64] (256^2)   [1024 blocks]
  convs2_nhwc_k<16, 16, 0, 16, 64, 32, 2, 256><<<dim3(8, 32, 4), 256, 0, stream>>>(
      ntN, ws + OFF_WD1, b_d1, d1cN);
  // d2: d1cat[32:64] -> d2cat[64:128] (128^2) [1024 blocks]
  convs2_nhwc_k<32, 64, 32, 8, 128, 64, 8, 128><<<dim3(4, 16, 16), 256, 0, stream>>>(
      d1cN, ws + OFF_WD2, b_d2, d2cN);
  // d3: d2cat[64:128] -> d3 (64^2)            [512 blocks]
  convs2_nhwc_k<64, 128, 64, 8, 128, 0, 16, 64><<<dim3(2, 8, 32), 256, 0, stream>>>(
      d2cN, ws + OFF_WD3, b_d3, d3N);
  // u3: up2(d3) -> d2cat[0:64] (128^2)        [512 blocks]
  convup_nhwc_k<128, 128, 0, 4, 128, 0, 16, 64><<<dim3(4, 4, 32), 256, 0, stream>>>(
      d3N, ws + OFF_WU3, b_u3, d2cN);
  // u2: up2(d2cat) -> d1cat[0:32] (256^2)     [1024 blocks]
  convup_nhwc_k<128, 128, 0, 4, 64, 0, 8, 128><<<dim3(8, 8, 16), 256, 0, stream>>>(
      d2cN, ws + OFF_WU2, b_u2, d1cN);
  // u1: up2(d1cat) 64->27 fused with final    [1024 blocks]
  convup_fuse_nhwc_k<<<dim3(16, 32, 2), 256, 0, stream>>>(
      d1cN, ws + OFF_WU1, b_u1, mN, albN, out + OUT_FINAL);
}